// Round 3
// baseline (2666.471 us; speedup 1.0000x reference)
//
#include <hip/hip_runtime.h>

#define NU 200000
#define NI 200000
#define NN 400000          // NU + NI (unified node space: users 0..NU-1, items NU..NN-1)
#define H 64
#define NE 4000000
#define NP 100000
#define EPSF 1e-5f

#define BSH 9              // nodes per bucket = 512
#define BNODES 512
#define NB ((NN + BNODES - 1) / BNODES)   // 782 buckets
#define CAP 15104          // LDS adj staging entries per bucket (mean 10230, sigma ~101)

// ================= CSR build =================

// ---- K0: per-bucket entry counts (each edge contributes 2 entries) ----
__global__ __launch_bounds__(256) void bucket_count_kernel(
    const int* __restrict__ src, const int* __restrict__ dst,
    int* __restrict__ g_bcnt)
{
    __shared__ int hist[NB];
    int tid = threadIdx.x;
    for (int i = tid; i < NB; i += 256) hist[i] = 0;
    __syncthreads();
    for (int e = blockIdx.x * 256 + tid; e < NE; e += gridDim.x * 256) {
        int s = src[e], d = dst[e];
        atomicAdd(&hist[s >> BSH], 1);
        atomicAdd(&hist[(NU + d) >> BSH], 1);
    }
    __syncthreads();
    for (int i = tid; i < NB; i += 256) atomicAdd(&g_bcnt[i], hist[i]);
}

// ---- K1: scan bucket counts -> bucket offsets + cursors (1 block) ----
__global__ __launch_bounds__(1024) void bucket_scan_kernel(
    const int* __restrict__ g_bcnt, int* __restrict__ g_boff,
    int* __restrict__ g_bcur)
{
    __shared__ int s[1024];
    int tid = threadIdx.x;
    int v = (tid < NB) ? g_bcnt[tid] : 0;
    s[tid] = v;
    __syncthreads();
    for (int d = 1; d < 1024; d <<= 1) {
        int t = (tid >= d) ? s[tid - d] : 0;
        __syncthreads();
        s[tid] += t;
        __syncthreads();
    }
    if (tid < NB) {
        g_boff[tid + 1] = s[tid];
        g_bcur[tid] = s[tid] - v;   // exclusive
    }
    if (tid == 0) g_boff[0] = 0;
}

// ---- K2: partition edge entries into bucket-contiguous staging ----
// entry = (local_node << 18) | neighbor   (local<512 -> 9 bits, nbr<200000 -> 18 bits)
__global__ __launch_bounds__(256) void partition_kernel(
    const int* __restrict__ src, const int* __restrict__ dst,
    int* __restrict__ g_bcur, int* __restrict__ staging)
{
    int e = blockIdx.x * 256 + threadIdx.x;
    if (e >= NE) return;
    int s = src[e], d = dst[e];
    int p1 = atomicAdd(&g_bcur[s >> BSH], 1);
    staging[p1] = ((s & (BNODES - 1)) << 18) | d;
    int gn = NU + d;
    int p2 = atomicAdd(&g_bcur[gn >> BSH], 1);
    staging[p2] = ((gn & (BNODES - 1)) << 18) | s;
}

// ---- K3: per-bucket CSR fill (LDS scatter + coalesced stream-out) ----
__global__ __launch_bounds__(256) void bucket_fill_kernel(
    const int* __restrict__ g_boff, const int* __restrict__ staging,
    int* __restrict__ off, int* __restrict__ adj)
{
    __shared__ int hist[BNODES];     // becomes exclusive offsets, then cursors
    __shared__ int psum[256];
    __shared__ int adj_st[CAP];
    int tid = threadIdx.x;
    int b = blockIdx.x;
    int e0 = g_boff[b], e1 = g_boff[b + 1];
    int cnt = e1 - e0;
    int node_base = b * BNODES;

    hist[tid] = 0; hist[tid + 256] = 0;
    __syncthreads();
    for (int i = tid; i < cnt; i += 256)
        atomicAdd(&hist[staging[e0 + i] >> 18], 1);
    __syncthreads();

    int h0 = hist[2 * tid], h1 = hist[2 * tid + 1];
    psum[tid] = h0 + h1;
    __syncthreads();
    for (int d = 1; d < 256; d <<= 1) {
        int t = (tid >= d) ? psum[tid - d] : 0;
        __syncthreads();
        psum[tid] += t;
        __syncthreads();
    }
    int ex0 = psum[tid] - (h0 + h1);
    int ex1 = ex0 + h0;
    int n0 = node_base + 2 * tid;
    if (n0 < NN)     off[n0]     = e0 + ex0;
    if (n0 + 1 < NN) off[n0 + 1] = e0 + ex1;
    if (b == NB - 1 && tid == 0) off[NN] = e1;
    __syncthreads();
    hist[2 * tid] = ex0; hist[2 * tid + 1] = ex1;   // reuse as cursors
    __syncthreads();

    if (cnt <= CAP) {
        for (int i = tid; i < cnt; i += 256) {
            int v = staging[e0 + i];
            int p = atomicAdd(&hist[v >> 18], 1);
            adj_st[p] = v & 0x3FFFF;
        }
        __syncthreads();
        for (int i = tid; i < cnt; i += 256) adj[e0 + i] = adj_st[i];
    } else {  // statistically unreachable fallback
        for (int i = tid; i < cnt; i += 256) {
            int v = staging[e0 + i];
            int p = atomicAdd(&hist[v >> 18], 1);
            adj[e0 + p] = v & 0x3FFFF;
        }
    }
}

// ================= pull aggregation (one wave per node, writes mean) =================
__global__ __launch_bounds__(256) void pull_kernel(
    const int* __restrict__ off, const int* __restrict__ adj,
    const float* __restrict__ xu, const float* __restrict__ xi,
    float* __restrict__ agg_u, float* __restrict__ agg_i)
{
    int wid = (int)((blockIdx.x * 256 + threadIdx.x) >> 6);
    int lane = threadIdx.x & 63;
    if (wid >= NN) return;
    const float* table;
    float* out;
    int node;
    if (wid < NU) { node = wid;      table = xi; out = agg_u; }
    else          { node = wid - NU; table = xu; out = agg_i; }
    int beg = off[wid], end = off[wid + 1];
    float a0 = 0.f, a1 = 0.f, a2 = 0.f, a3 = 0.f;
    for (int k = beg; k < end; k += 64) {
        int nk = min(64, end - k);
        int nb = (lane < nk) ? adj[k + lane] : 0;
        int t = 0;
        for (; t + 4 <= nk; t += 4) {
            int n0 = __shfl(nb, t);
            int n1 = __shfl(nb, t + 1);
            int n2 = __shfl(nb, t + 2);
            int n3 = __shfl(nb, t + 3);
            a0 += table[(size_t)n0 * H + lane];
            a1 += table[(size_t)n1 * H + lane];
            a2 += table[(size_t)n2 * H + lane];
            a3 += table[(size_t)n3 * H + lane];
        }
        for (; t < nk; ++t)
            a0 += table[(size_t)__shfl(nb, t) * H + lane];
    }
    float s = (a0 + a1) + (a2 + a3);
    int deg = end - beg;
    out[(size_t)node * H + lane] = s / fmaxf((float)deg, 1.0f);
}

// ================= register-tiled node update =================
// relu(bn(agg_mean @ Wll + bll + x @ Wlr)); 64 nodes x 64 feats per block,
// thread = 4 nodes x 4 feats, k in 2 halves of 32, ds_read_b128 everywhere.
// n_nodes must be a multiple of 64 (200000 = 3125*64).
__global__ __launch_bounds__(256) void update_kernel(
    const float* __restrict__ agg, const float* __restrict__ x_in,
    float* __restrict__ x_out,
    const float* __restrict__ Wll, const float* __restrict__ bll,
    const float* __restrict__ Wlr,
    const float* __restrict__ bng, const float* __restrict__ bnb,
    const float* __restrict__ bnm, const float* __restrict__ bnv)
{
    __shared__ float sWll[32][68];
    __shared__ float sWlr[32][68];
    __shared__ float sA[64][36];
    __shared__ float sX[64][36];
    int tid = threadIdx.x;
    int node0 = blockIdx.x * 64;
    int jt = (tid & 15) * 4;
    int nt = (tid >> 4) * 4;

    float4 b4 = *(const float4*)&bll[jt];
    float acc[4][4];
#pragma unroll
    for (int i = 0; i < 4; ++i) {
        acc[i][0] = b4.x; acc[i][1] = b4.y; acc[i][2] = b4.z; acc[i][3] = b4.w;
    }

    for (int kh = 0; kh < 2; ++kh) {
        int k0 = kh * 32;
        for (int idx = tid; idx < 32 * 64; idx += 256) {
            int kk = idx >> 6, j = idx & 63;
            sWll[kk][j] = Wll[(k0 + kk) * 64 + j];
            sWlr[kk][j] = Wlr[(k0 + kk) * 64 + j];
        }
        for (int idx = tid; idx < 64 * 32; idx += 256) {
            int r = idx >> 5, c = idx & 31;
            sA[r][c] = agg[(size_t)(node0 + r) * H + k0 + c];
            sX[r][c] = x_in[(size_t)(node0 + r) * H + k0 + c];
        }
        __syncthreads();
        for (int kk = 0; kk < 32; kk += 4) {
            float a[4][4], x[4][4];
#pragma unroll
            for (int i = 0; i < 4; ++i) {
                float4 t = *(const float4*)&sA[nt + i][kk];
                a[i][0] = t.x; a[i][1] = t.y; a[i][2] = t.z; a[i][3] = t.w;
                float4 u = *(const float4*)&sX[nt + i][kk];
                x[i][0] = u.x; x[i][1] = u.y; x[i][2] = u.z; x[i][3] = u.w;
            }
#pragma unroll
            for (int q = 0; q < 4; ++q) {
                float4 wl = *(const float4*)&sWll[kk + q][jt];
                float4 wr = *(const float4*)&sWlr[kk + q][jt];
                float wlv[4] = {wl.x, wl.y, wl.z, wl.w};
                float wrv[4] = {wr.x, wr.y, wr.z, wr.w};
#pragma unroll
                for (int i = 0; i < 4; ++i)
#pragma unroll
                    for (int j = 0; j < 4; ++j)
                        acc[i][j] += a[i][q] * wlv[j] + x[i][q] * wrv[j];
            }
        }
        __syncthreads();
    }

    float4 g4 = *(const float4*)&bng[jt];
    float4 bb4 = *(const float4*)&bnb[jt];
    float4 m4 = *(const float4*)&bnm[jt];
    float4 v4 = *(const float4*)&bnv[jt];
    float gv[4] = {g4.x, g4.y, g4.z, g4.w};
    float bv[4] = {bb4.x, bb4.y, bb4.z, bb4.w};
    float mv[4] = {m4.x, m4.y, m4.z, m4.w};
    float rv[4] = {rsqrtf(v4.x + EPSF), rsqrtf(v4.y + EPSF),
                   rsqrtf(v4.z + EPSF), rsqrtf(v4.w + EPSF)};
#pragma unroll
    for (int i = 0; i < 4; ++i) {
        int node = node0 + nt + i;
        float4 o;
        o.x = fmaxf((acc[i][0] - mv[0]) * rv[0] * gv[0] + bv[0], 0.f);
        o.y = fmaxf((acc[i][1] - mv[1]) * rv[1] * gv[1] + bv[1], 0.f);
        o.z = fmaxf((acc[i][2] - mv[2]) * rv[2] * gv[2] + bv[2], 0.f);
        o.w = fmaxf((acc[i][3] - mv[3]) * rv[3] * gv[3] + bv[3], 0.f);
        *(float4*)&x_out[(size_t)node * H + jt] = o;
    }
}

// ================= MLP head (register-tiled fc1, LDS fc2) =================
__global__ __launch_bounds__(256) void mlp_kernel(
    const int* __restrict__ eli,
    const float* __restrict__ xu, const float* __restrict__ xi,
    const float* __restrict__ fc1w, const float* __restrict__ fc1b,
    const float* __restrict__ fc2w, const float* __restrict__ fc2b,
    float* __restrict__ out, int n)
{
    __shared__ float sW[32][68];
    __shared__ float sA[64][36];
    __shared__ float sH[64][68];
    __shared__ int   sid[128];
    __shared__ float sW2[256];
    int tid = threadIdx.x;
    int p0 = blockIdx.x * 64;
    if (tid < 128) {
        int p = p0 + (tid & 63);
        int side = tid >> 6;
        sid[tid] = (p < n) ? eli[side * NP + p] : -1;
    }
    sW2[tid] = fc2w[tid];
    __syncthreads();

    int jt = (tid & 15) * 4;
    int pt = (tid >> 4) * 4;
    float4 b4 = *(const float4*)&fc1b[jt];
    float acc[4][4];
#pragma unroll
    for (int i = 0; i < 4; ++i) {
        acc[i][0] = b4.x; acc[i][1] = b4.y; acc[i][2] = b4.z; acc[i][3] = b4.w;
    }

    for (int ch = 0; ch < 4; ++ch) {
        int k0 = ch * 32;
        const float* tab = (ch < 2) ? xu : xi;
        int idbase = (ch < 2) ? 0 : 64;
        int koff = (ch & 1) * 32;
        for (int idx = tid; idx < 64 * 32; idx += 256) {
            int r = idx >> 5, c = idx & 31;
            int id = sid[idbase + r];
            sA[r][c] = (id >= 0) ? tab[(size_t)id * H + koff + c] : 0.f;
        }
        for (int idx = tid; idx < 32 * 64; idx += 256) {
            int kk = idx >> 6, j = idx & 63;
            sW[kk][j] = fc1w[(k0 + kk) * 64 + j];
        }
        __syncthreads();
        for (int kk = 0; kk < 32; kk += 4) {
            float a[4][4];
#pragma unroll
            for (int i = 0; i < 4; ++i) {
                float4 t = *(const float4*)&sA[pt + i][kk];
                a[i][0] = t.x; a[i][1] = t.y; a[i][2] = t.z; a[i][3] = t.w;
            }
#pragma unroll
            for (int q = 0; q < 4; ++q) {
                float4 w = *(const float4*)&sW[kk + q][jt];
                float wv[4] = {w.x, w.y, w.z, w.w};
#pragma unroll
                for (int i = 0; i < 4; ++i)
#pragma unroll
                    for (int j = 0; j < 4; ++j)
                        acc[i][j] += a[i][q] * wv[j];
            }
        }
        __syncthreads();
    }

#pragma unroll
    for (int i = 0; i < 4; ++i)
#pragma unroll
        for (int j = 0; j < 4; ++j)
            sH[pt + i][jt + j] = fmaxf(acc[i][j], 0.f);
    __syncthreads();

    int pp = tid >> 2, c = tid & 3;
    float o = 0.f;
#pragma unroll
    for (int j = 0; j < 64; ++j) o += sH[pp][j] * sW2[j * 4 + c];
    int p = p0 + pp;
    if (p < n) out[(size_t)p * 4 + c] = o + fc2b[c];
}

extern "C" void kernel_launch(void* const* d_in, const int* in_sizes, int n_in,
                              void* d_out, int out_size, void* d_ws, size_t ws_size,
                              hipStream_t stream) {
    const int*   edge_index = (const int*)d_in[0];
    const int*   eli        = (const int*)d_in[1];
    const float* user_emb   = (const float*)d_in[2];
    const float* item_emb   = (const float*)d_in[3];
    const float* u_ll_w     = (const float*)d_in[4];
    const float* u_ll_b     = (const float*)d_in[5];
    const float* u_lr_w     = (const float*)d_in[6];
    const float* i_ll_w     = (const float*)d_in[7];
    const float* i_ll_b     = (const float*)d_in[8];
    const float* i_lr_w     = (const float*)d_in[9];
    const float* u_bn_g     = (const float*)d_in[10];
    const float* u_bn_b     = (const float*)d_in[11];
    const float* u_bn_m     = (const float*)d_in[12];
    const float* u_bn_v     = (const float*)d_in[13];
    const float* i_bn_g     = (const float*)d_in[14];
    const float* i_bn_b     = (const float*)d_in[15];
    const float* i_bn_m     = (const float*)d_in[16];
    const float* i_bn_v     = (const float*)d_in[17];
    const float* fc1_w      = (const float*)d_in[18];
    const float* fc1_b      = (const float*)d_in[19];
    const float* fc2_w      = (const float*)d_in[20];
    const float* fc2_b      = (const float*)d_in[21];
    float* out = (float*)d_out;

    const int* src = edge_index;
    const int* dst = edge_index + NE;

    // workspace layout
    char* w = (char*)d_ws;
    float* bufA_u = (float*)w;  w += (size_t)NU * H * 4;
    float* bufA_i = (float*)w;  w += (size_t)NI * H * 4;
    float* bufB_u = (float*)w;  w += (size_t)NU * H * 4;
    float* bufB_i = (float*)w;  w += (size_t)NI * H * 4;
    int* adj    = (int*)w;      w += (size_t)2 * NE * 4;
    int* off    = (int*)w;      w += (size_t)(NN + 1) * 4;
    int* g_bcnt = (int*)w;      w += (size_t)NB * 4;
    int* g_boff = (int*)w;      w += (size_t)(NB + 1) * 4;
    int* g_bcur = (int*)w;      w += (size_t)NB * 4;
    // staging (8M ints = 32 MB) aliases bufB_u (51.2 MB): CSR build completes
    // before layer-1 writes bufB.
    int* staging = (int*)bufB_u;

    // ---- CSR build ----
    hipMemsetAsync(g_bcnt, 0, (size_t)NB * 4, stream);
    bucket_count_kernel<<<1024, 256, 0, stream>>>(src, dst, g_bcnt);
    bucket_scan_kernel<<<1, 1024, 0, stream>>>(g_bcnt, g_boff, g_bcur);
    partition_kernel<<<(NE + 255) / 256, 256, 0, stream>>>(src, dst, g_bcur, staging);
    bucket_fill_kernel<<<NB, 256, 0, stream>>>(g_boff, staging, off, adj);

    const int pull_blocks = NN / 4;

    // ---- layer 0 ----
    pull_kernel<<<pull_blocks, 256, 0, stream>>>(
        off, adj, user_emb, item_emb, bufA_u, bufA_i);
    update_kernel<<<NU / 64, 256, 0, stream>>>(
        bufA_u, user_emb, bufA_u,
        u_ll_w, u_ll_b, u_lr_w, u_bn_g, u_bn_b, u_bn_m, u_bn_v);
    update_kernel<<<NI / 64, 256, 0, stream>>>(
        bufA_i, item_emb, bufA_i,
        i_ll_w, i_ll_b, i_lr_w, i_bn_g, i_bn_b, i_bn_m, i_bn_v);

    // ---- layer 1 ----
    pull_kernel<<<pull_blocks, 256, 0, stream>>>(
        off, adj, bufA_u, bufA_i, bufB_u, bufB_i);
    update_kernel<<<NU / 64, 256, 0, stream>>>(
        bufB_u, bufA_u, bufB_u,
        u_ll_w + H * H, u_ll_b + H, u_lr_w + H * H,
        u_bn_g + H, u_bn_b + H, u_bn_m + H, u_bn_v + H);
    update_kernel<<<NI / 64, 256, 0, stream>>>(
        bufB_i, bufA_i, bufB_i,
        i_ll_w + H * H, i_ll_b + H, i_lr_w + H * H,
        i_bn_g + H, i_bn_b + H, i_bn_m + H, i_bn_v + H);

    // ---- MLP head ----
    mlp_kernel<<<(NP + 63) / 64, 256, 0, stream>>>(
        eli, bufB_u, bufB_i, fc1_w, fc1_b, fc2_w, fc2_b, out, NP);
}

// Round 4
// 2660.905 us; speedup vs baseline: 1.0021x; 1.0021x over previous
//
#include <hip/hip_runtime.h>

#define NU 200000
#define NI 200000
#define NN 400000          // NU + NI (unified node space: users 0..NU-1, items NU..NN-1)
#define H 64
#define NE 4000000
#define NP 100000
#define EPSF 1e-5f

#define BSH 9              // nodes per bucket = 512
#define BNODES 512
#define NB ((NN + BNODES - 1) / BNODES)   // 782 buckets
#define CAP 15104          // LDS adj staging entries per bucket (mean 10230, sigma ~101)

// ================= CSR build =================

// ---- K0: per-bucket entry counts (each edge contributes 2 entries) ----
__global__ __launch_bounds__(256) void bucket_count_kernel(
    const int* __restrict__ src, const int* __restrict__ dst,
    int* __restrict__ g_bcnt)
{
    __shared__ int hist[NB];
    int tid = threadIdx.x;
    for (int i = tid; i < NB; i += 256) hist[i] = 0;
    __syncthreads();
    for (int e = blockIdx.x * 256 + tid; e < NE; e += gridDim.x * 256) {
        int s = src[e], d = dst[e];
        atomicAdd(&hist[s >> BSH], 1);
        atomicAdd(&hist[(NU + d) >> BSH], 1);
    }
    __syncthreads();
    for (int i = tid; i < NB; i += 256) atomicAdd(&g_bcnt[i], hist[i]);
}

// ---- K1: scan bucket counts -> bucket offsets + cursors (1 block) ----
__global__ __launch_bounds__(1024) void bucket_scan_kernel(
    const int* __restrict__ g_bcnt, int* __restrict__ g_boff,
    int* __restrict__ g_bcur)
{
    __shared__ int s[1024];
    int tid = threadIdx.x;
    int v = (tid < NB) ? g_bcnt[tid] : 0;
    s[tid] = v;
    __syncthreads();
    for (int d = 1; d < 1024; d <<= 1) {
        int t = (tid >= d) ? s[tid - d] : 0;
        __syncthreads();
        s[tid] += t;
        __syncthreads();
    }
    if (tid < NB) {
        g_boff[tid + 1] = s[tid];
        g_bcur[tid] = s[tid] - v;   // exclusive
    }
    if (tid == 0) g_boff[0] = 0;
}

// ---- K2: partition edge entries into bucket-contiguous staging ----
// entry = (local_node << 18) | neighbor   (local<512 -> 9 bits, nbr<200000 -> 18 bits)
__global__ __launch_bounds__(256) void partition_kernel(
    const int* __restrict__ src, const int* __restrict__ dst,
    int* __restrict__ g_bcur, int* __restrict__ staging)
{
    int e = blockIdx.x * 256 + threadIdx.x;
    if (e >= NE) return;
    int s = src[e], d = dst[e];
    int p1 = atomicAdd(&g_bcur[s >> BSH], 1);
    staging[p1] = ((s & (BNODES - 1)) << 18) | d;
    int gn = NU + d;
    int p2 = atomicAdd(&g_bcur[gn >> BSH], 1);
    staging[p2] = ((gn & (BNODES - 1)) << 18) | s;
}

// ---- K3: per-bucket CSR fill (LDS scatter + coalesced stream-out) ----
__global__ __launch_bounds__(256) void bucket_fill_kernel(
    const int* __restrict__ g_boff, const int* __restrict__ staging,
    int* __restrict__ off, int* __restrict__ adj)
{
    __shared__ int hist[BNODES];     // becomes exclusive offsets, then cursors
    __shared__ int psum[256];
    __shared__ int adj_st[CAP];
    int tid = threadIdx.x;
    int b = blockIdx.x;
    int e0 = g_boff[b], e1 = g_boff[b + 1];
    int cnt = e1 - e0;
    int node_base = b * BNODES;

    hist[tid] = 0; hist[tid + 256] = 0;
    __syncthreads();
    for (int i = tid; i < cnt; i += 256)
        atomicAdd(&hist[staging[e0 + i] >> 18], 1);
    __syncthreads();

    int h0 = hist[2 * tid], h1 = hist[2 * tid + 1];
    psum[tid] = h0 + h1;
    __syncthreads();
    for (int d = 1; d < 256; d <<= 1) {
        int t = (tid >= d) ? psum[tid - d] : 0;
        __syncthreads();
        psum[tid] += t;
        __syncthreads();
    }
    int ex0 = psum[tid] - (h0 + h1);
    int ex1 = ex0 + h0;
    int n0 = node_base + 2 * tid;
    if (n0 < NN)     off[n0]     = e0 + ex0;
    if (n0 + 1 < NN) off[n0 + 1] = e0 + ex1;
    if (b == NB - 1 && tid == 0) off[NN] = e1;
    __syncthreads();
    hist[2 * tid] = ex0; hist[2 * tid + 1] = ex1;   // reuse as cursors
    __syncthreads();

    if (cnt <= CAP) {
        for (int i = tid; i < cnt; i += 256) {
            int v = staging[e0 + i];
            int p = atomicAdd(&hist[v >> 18], 1);
            adj_st[p] = v & 0x3FFFF;
        }
        __syncthreads();
        for (int i = tid; i < cnt; i += 256) adj[e0 + i] = adj_st[i];
    } else {  // statistically unreachable fallback
        for (int i = tid; i < cnt; i += 256) {
            int v = staging[e0 + i];
            int p = atomicAdd(&hist[v >> 18], 1);
            adj[e0 + p] = v & 0x3FFFF;
        }
    }
}

// ================= pull aggregation (one wave per node, writes mean) =================
__global__ __launch_bounds__(256) void pull_kernel(
    const int* __restrict__ off, const int* __restrict__ adj,
    const float* __restrict__ xu, const float* __restrict__ xi,
    float* __restrict__ agg_u, float* __restrict__ agg_i)
{
    int wid = (int)((blockIdx.x * 256 + threadIdx.x) >> 6);
    int lane = threadIdx.x & 63;
    if (wid >= NN) return;
    const float* table;
    float* out;
    int node;
    if (wid < NU) { node = wid;      table = xi; out = agg_u; }
    else          { node = wid - NU; table = xu; out = agg_i; }
    int beg = off[wid], end = off[wid + 1];
    float a0 = 0.f, a1 = 0.f, a2 = 0.f, a3 = 0.f;
    for (int k = beg; k < end; k += 64) {
        int nk = min(64, end - k);
        int nb = (lane < nk) ? adj[k + lane] : 0;
        int t = 0;
        for (; t + 4 <= nk; t += 4) {
            int n0 = __shfl(nb, t);
            int n1 = __shfl(nb, t + 1);
            int n2 = __shfl(nb, t + 2);
            int n3 = __shfl(nb, t + 3);
            a0 += table[(size_t)n0 * H + lane];
            a1 += table[(size_t)n1 * H + lane];
            a2 += table[(size_t)n2 * H + lane];
            a3 += table[(size_t)n3 * H + lane];
        }
        for (; t < nk; ++t)
            a0 += table[(size_t)__shfl(nb, t) * H + lane];
    }
    float s = (a0 + a1) + (a2 + a3);
    int deg = end - beg;
    out[(size_t)node * H + lane] = s / fmaxf((float)deg, 1.0f);
}

// ================= register-tiled node update =================
// relu(bn(agg_mean @ Wll + bll + x @ Wlr)); 64 nodes x 64 feats per block,
// thread = 4 nodes x 4 feats, k in 2 halves of 32, ds_read_b128 everywhere.
// n_nodes must be a multiple of 64 (200000 = 3125*64).
__global__ __launch_bounds__(256) void update_kernel(
    const float* __restrict__ agg, const float* __restrict__ x_in,
    float* __restrict__ x_out,
    const float* __restrict__ Wll, const float* __restrict__ bll,
    const float* __restrict__ Wlr,
    const float* __restrict__ bng, const float* __restrict__ bnb,
    const float* __restrict__ bnm, const float* __restrict__ bnv)
{
    __shared__ float sWll[32][68];
    __shared__ float sWlr[32][68];
    __shared__ float sA[64][36];
    __shared__ float sX[64][36];
    int tid = threadIdx.x;
    int node0 = blockIdx.x * 64;
    int jt = (tid & 15) * 4;
    int nt = (tid >> 4) * 4;

    float4 b4 = *(const float4*)&bll[jt];
    float acc[4][4];
#pragma unroll
    for (int i = 0; i < 4; ++i) {
        acc[i][0] = b4.x; acc[i][1] = b4.y; acc[i][2] = b4.z; acc[i][3] = b4.w;
    }

    for (int kh = 0; kh < 2; ++kh) {
        int k0 = kh * 32;
        for (int idx = tid; idx < 32 * 64; idx += 256) {
            int kk = idx >> 6, j = idx & 63;
            sWll[kk][j] = Wll[(k0 + kk) * 64 + j];
            sWlr[kk][j] = Wlr[(k0 + kk) * 64 + j];
        }
        for (int idx = tid; idx < 64 * 32; idx += 256) {
            int r = idx >> 5, c = idx & 31;
            sA[r][c] = agg[(size_t)(node0 + r) * H + k0 + c];
            sX[r][c] = x_in[(size_t)(node0 + r) * H + k0 + c];
        }
        __syncthreads();
        for (int kk = 0; kk < 32; kk += 4) {
            float a[4][4], x[4][4];
#pragma unroll
            for (int i = 0; i < 4; ++i) {
                float4 t = *(const float4*)&sA[nt + i][kk];
                a[i][0] = t.x; a[i][1] = t.y; a[i][2] = t.z; a[i][3] = t.w;
                float4 u = *(const float4*)&sX[nt + i][kk];
                x[i][0] = u.x; x[i][1] = u.y; x[i][2] = u.z; x[i][3] = u.w;
            }
#pragma unroll
            for (int q = 0; q < 4; ++q) {
                float4 wl = *(const float4*)&sWll[kk + q][jt];
                float4 wr = *(const float4*)&sWlr[kk + q][jt];
                float wlv[4] = {wl.x, wl.y, wl.z, wl.w};
                float wrv[4] = {wr.x, wr.y, wr.z, wr.w};
#pragma unroll
                for (int i = 0; i < 4; ++i)
#pragma unroll
                    for (int j = 0; j < 4; ++j)
                        acc[i][j] += a[i][q] * wlv[j] + x[i][q] * wrv[j];
            }
        }
        __syncthreads();
    }

    float4 g4 = *(const float4*)&bng[jt];
    float4 bb4 = *(const float4*)&bnb[jt];
    float4 m4 = *(const float4*)&bnm[jt];
    float4 v4 = *(const float4*)&bnv[jt];
    float gv[4] = {g4.x, g4.y, g4.z, g4.w};
    float bv[4] = {bb4.x, bb4.y, bb4.z, bb4.w};
    float mv[4] = {m4.x, m4.y, m4.z, m4.w};
    float rv[4] = {rsqrtf(v4.x + EPSF), rsqrtf(v4.y + EPSF),
                   rsqrtf(v4.z + EPSF), rsqrtf(v4.w + EPSF)};
#pragma unroll
    for (int i = 0; i < 4; ++i) {
        int node = node0 + nt + i;
        float4 o;
        o.x = fmaxf((acc[i][0] - mv[0]) * rv[0] * gv[0] + bv[0], 0.f);
        o.y = fmaxf((acc[i][1] - mv[1]) * rv[1] * gv[1] + bv[1], 0.f);
        o.z = fmaxf((acc[i][2] - mv[2]) * rv[2] * gv[2] + bv[2], 0.f);
        o.w = fmaxf((acc[i][3] - mv[3]) * rv[3] * gv[3] + bv[3], 0.f);
        *(float4*)&x_out[(size_t)node * H + jt] = o;
    }
}

// ================= MLP head (register-tiled fc1, LDS fc2) =================
__global__ __launch_bounds__(256) void mlp_kernel(
    const int* __restrict__ eli,
    const float* __restrict__ xu, const float* __restrict__ xi,
    const float* __restrict__ fc1w, const float* __restrict__ fc1b,
    const float* __restrict__ fc2w, const float* __restrict__ fc2b,
    float* __restrict__ out, int n)
{
    __shared__ float sW[32][68];
    __shared__ float sA[64][36];
    __shared__ float sH[64][68];
    __shared__ int   sid[128];
    __shared__ float sW2[256];
    int tid = threadIdx.x;
    int p0 = blockIdx.x * 64;
    if (tid < 128) {
        int p = p0 + (tid & 63);
        int side = tid >> 6;
        sid[tid] = (p < n) ? eli[side * NP + p] : -1;
    }
    sW2[tid] = fc2w[tid];
    __syncthreads();

    int jt = (tid & 15) * 4;
    int pt = (tid >> 4) * 4;
    float4 b4 = *(const float4*)&fc1b[jt];
    float acc[4][4];
#pragma unroll
    for (int i = 0; i < 4; ++i) {
        acc[i][0] = b4.x; acc[i][1] = b4.y; acc[i][2] = b4.z; acc[i][3] = b4.w;
    }

    for (int ch = 0; ch < 4; ++ch) {
        int k0 = ch * 32;
        const float* tab = (ch < 2) ? xu : xi;
        int idbase = (ch < 2) ? 0 : 64;
        int koff = (ch & 1) * 32;
        for (int idx = tid; idx < 64 * 32; idx += 256) {
            int r = idx >> 5, c = idx & 31;
            int id = sid[idbase + r];
            sA[r][c] = (id >= 0) ? tab[(size_t)id * H + koff + c] : 0.f;
        }
        for (int idx = tid; idx < 32 * 64; idx += 256) {
            int kk = idx >> 6, j = idx & 63;
            sW[kk][j] = fc1w[(k0 + kk) * 64 + j];
        }
        __syncthreads();
        for (int kk = 0; kk < 32; kk += 4) {
            float a[4][4];
#pragma unroll
            for (int i = 0; i < 4; ++i) {
                float4 t = *(const float4*)&sA[pt + i][kk];
                a[i][0] = t.x; a[i][1] = t.y; a[i][2] = t.z; a[i][3] = t.w;
            }
#pragma unroll
            for (int q = 0; q < 4; ++q) {
                float4 w = *(const float4*)&sW[kk + q][jt];
                float wv[4] = {w.x, w.y, w.z, w.w};
#pragma unroll
                for (int i = 0; i < 4; ++i)
#pragma unroll
                    for (int j = 0; j < 4; ++j)
                        acc[i][j] += a[i][q] * wv[j];
            }
        }
        __syncthreads();
    }

#pragma unroll
    for (int i = 0; i < 4; ++i)
#pragma unroll
        for (int j = 0; j < 4; ++j)
            sH[pt + i][jt + j] = fmaxf(acc[i][j], 0.f);
    __syncthreads();

    int pp = tid >> 2, c = tid & 3;
    float o = 0.f;
#pragma unroll
    for (int j = 0; j < 64; ++j) o += sH[pp][j] * sW2[j * 4 + c];
    int p = p0 + pp;
    if (p < n) out[(size_t)p * 4 + c] = o + fc2b[c];
}

extern "C" void kernel_launch(void* const* d_in, const int* in_sizes, int n_in,
                              void* d_out, int out_size, void* d_ws, size_t ws_size,
                              hipStream_t stream) {
    const int*   edge_index = (const int*)d_in[0];
    const int*   eli        = (const int*)d_in[1];
    const float* user_emb   = (const float*)d_in[2];
    const float* item_emb   = (const float*)d_in[3];
    const float* u_ll_w     = (const float*)d_in[4];
    const float* u_ll_b     = (const float*)d_in[5];
    const float* u_lr_w     = (const float*)d_in[6];
    const float* i_ll_w     = (const float*)d_in[7];
    const float* i_ll_b     = (const float*)d_in[8];
    const float* i_lr_w     = (const float*)d_in[9];
    const float* u_bn_g     = (const float*)d_in[10];
    const float* u_bn_b     = (const float*)d_in[11];
    const float* u_bn_m     = (const float*)d_in[12];
    const float* u_bn_v     = (const float*)d_in[13];
    const float* i_bn_g     = (const float*)d_in[14];
    const float* i_bn_b     = (const float*)d_in[15];
    const float* i_bn_m     = (const float*)d_in[16];
    const float* i_bn_v     = (const float*)d_in[17];
    const float* fc1_w      = (const float*)d_in[18];
    const float* fc1_b      = (const float*)d_in[19];
    const float* fc2_w      = (const float*)d_in[20];
    const float* fc2_b      = (const float*)d_in[21];
    float* out = (float*)d_out;

    const int* src = edge_index;
    const int* dst = edge_index + NE;

    // workspace layout
    char* w = (char*)d_ws;
    float* bufA_u = (float*)w;  w += (size_t)NU * H * 4;
    float* bufA_i = (float*)w;  w += (size_t)NI * H * 4;
    float* bufB_u = (float*)w;  w += (size_t)NU * H * 4;
    float* bufB_i = (float*)w;  w += (size_t)NI * H * 4;
    int* adj    = (int*)w;      w += (size_t)2 * NE * 4;
    int* off    = (int*)w;      w += (size_t)(NN + 1) * 4;
    int* g_bcnt = (int*)w;      w += (size_t)NB * 4;
    int* g_boff = (int*)w;      w += (size_t)(NB + 1) * 4;
    int* g_bcur = (int*)w;      w += (size_t)NB * 4;
    // staging (8M ints = 32 MB) aliases bufB_u (51.2 MB): CSR build completes
    // before layer-1 writes bufB.
    int* staging = (int*)bufB_u;

    // ---- CSR build ----
    hipMemsetAsync(g_bcnt, 0, (size_t)NB * 4, stream);
    bucket_count_kernel<<<1024, 256, 0, stream>>>(src, dst, g_bcnt);
    bucket_scan_kernel<<<1, 1024, 0, stream>>>(g_bcnt, g_boff, g_bcur);
    partition_kernel<<<(NE + 255) / 256, 256, 0, stream>>>(src, dst, g_bcur, staging);
    bucket_fill_kernel<<<NB, 256, 0, stream>>>(g_boff, staging, off, adj);

    const int pull_blocks = NN / 4;

    // ---- layer 0 ----
    pull_kernel<<<pull_blocks, 256, 0, stream>>>(
        off, adj, user_emb, item_emb, bufA_u, bufA_i);
    update_kernel<<<NU / 64, 256, 0, stream>>>(
        bufA_u, user_emb, bufA_u,
        u_ll_w, u_ll_b, u_lr_w, u_bn_g, u_bn_b, u_bn_m, u_bn_v);
    update_kernel<<<NI / 64, 256, 0, stream>>>(
        bufA_i, item_emb, bufA_i,
        i_ll_w, i_ll_b, i_lr_w, i_bn_g, i_bn_b, i_bn_m, i_bn_v);

    // ---- layer 1 ----
    pull_kernel<<<pull_blocks, 256, 0, stream>>>(
        off, adj, bufA_u, bufA_i, bufB_u, bufB_i);
    update_kernel<<<NU / 64, 256, 0, stream>>>(
        bufB_u, bufA_u, bufB_u,
        u_ll_w + H * H, u_ll_b + H, u_lr_w + H * H,
        u_bn_g + H, u_bn_b + H, u_bn_m + H, u_bn_v + H);
    update_kernel<<<NI / 64, 256, 0, stream>>>(
        bufB_i, bufA_i, bufB_i,
        i_ll_w + H * H, i_ll_b + H, i_lr_w + H * H,
        i_bn_g + H, i_bn_b + H, i_bn_m + H, i_bn_v + H);

    // ---- MLP head ----
    mlp_kernel<<<(NP + 63) / 64, 256, 0, stream>>>(
        eli, bufB_u, bufB_i, fc1_w, fc1_b, fc2_w, fc2_b, out, NP);
}

// Round 5
// 1133.499 us; speedup vs baseline: 2.3524x; 2.3475x over previous
//
#include <hip/hip_runtime.h>

#define NU 200000
#define NI 200000
#define NN 400000          // NU + NI (unified node space: users 0..NU-1, items NU..NN-1)
#define H 64
#define NE 4000000
#define NP 100000
#define EPSF 1e-5f

#define BSH 9              // nodes per bucket = 512
#define BNODES 512
#define NB ((NN + BNODES - 1) / BNODES)   // 782 buckets
#define CAP 15104          // LDS adj staging entries per bucket (mean 10240, sigma ~101)

#define PBLOCKS 512                          // partition blocks
#define EPB ((NE + PBLOCKS - 1) / PBLOCKS)   // 7813 edges per block slice

// ================= CSR build (two-phase, LDS-atomic-only) =================

// ---- K0: per-(bucket, block) entry counts ----
__global__ __launch_bounds__(256) void part1_kernel(
    const int* __restrict__ src, const int* __restrict__ dst,
    int* __restrict__ blkhist)
{
    __shared__ int hist[NB];
    int tid = threadIdx.x, blk = blockIdx.x;
    for (int i = tid; i < NB; i += 256) hist[i] = 0;
    __syncthreads();
    int e0 = blk * EPB, e1 = min(NE, e0 + EPB);
    for (int e = e0 + tid; e < e1; e += 256) {
        atomicAdd(&hist[src[e] >> BSH], 1);
        atomicAdd(&hist[(NU + dst[e]) >> BSH], 1);
    }
    __syncthreads();
    for (int i = tid; i < NB; i += 256)
        blkhist[(size_t)i * PBLOCKS + blk] = hist[i];
}

// ---- K1: per-bucket exclusive scan over its PBLOCKS counts; emit totals ----
__global__ __launch_bounds__(256) void colscan_kernel(
    int* __restrict__ blkhist, int* __restrict__ g_bcnt)
{
    __shared__ int s[256];
    int b = blockIdx.x, tid = threadIdx.x;
    int* col = blkhist + (size_t)b * PBLOCKS;
    int v0 = col[2 * tid], v1 = col[2 * tid + 1];
    int ps = v0 + v1;
    s[tid] = ps;
    __syncthreads();
    for (int d = 1; d < 256; d <<= 1) {
        int t = (tid >= d) ? s[tid - d] : 0;
        __syncthreads();
        s[tid] += t;
        __syncthreads();
    }
    int ex = s[tid] - ps;   // exclusive over pairs
    col[2 * tid] = ex;
    col[2 * tid + 1] = ex + v0;
    if (tid == 255) g_bcnt[b] = s[255];
}

// ---- K2: exclusive scan of bucket totals -> bucket offsets (1 block) ----
__global__ __launch_bounds__(1024) void bucket_scan_kernel(
    const int* __restrict__ g_bcnt, int* __restrict__ g_boff)
{
    __shared__ int s[1024];
    int tid = threadIdx.x;
    int v = (tid < NB) ? g_bcnt[tid] : 0;
    s[tid] = v;
    __syncthreads();
    for (int d = 1; d < 1024; d <<= 1) {
        int t = (tid >= d) ? s[tid - d] : 0;
        __syncthreads();
        s[tid] += t;
        __syncthreads();
    }
    if (tid < NB) g_boff[tid + 1] = s[tid];
    if (tid == 0) g_boff[0] = 0;
}

// ---- K3: scatter entries to bucket-contiguous staging (LDS cursors only) ----
// entry = (local_node << 18) | neighbor   (local<512 -> 9 bits, nbr<200000 -> 18 bits)
__global__ __launch_bounds__(256) void part2_kernel(
    const int* __restrict__ src, const int* __restrict__ dst,
    const int* __restrict__ g_boff, const int* __restrict__ blkhist,
    int* __restrict__ staging)
{
    __shared__ int cur[NB];
    int tid = threadIdx.x, blk = blockIdx.x;
    for (int i = tid; i < NB; i += 256)
        cur[i] = g_boff[i] + blkhist[(size_t)i * PBLOCKS + blk];
    __syncthreads();
    int e0 = blk * EPB, e1 = min(NE, e0 + EPB);
    for (int e = e0 + tid; e < e1; e += 256) {
        int s = src[e], d = dst[e];
        int p1 = atomicAdd(&cur[s >> BSH], 1);
        staging[p1] = ((s & (BNODES - 1)) << 18) | d;
        int gn = NU + d;
        int p2 = atomicAdd(&cur[gn >> BSH], 1);
        staging[p2] = ((gn & (BNODES - 1)) << 18) | s;
    }
}

// ---- K4: per-bucket CSR fill (LDS scatter + coalesced stream-out) ----
__global__ __launch_bounds__(256) void bucket_fill_kernel(
    const int* __restrict__ g_boff, const int* __restrict__ staging,
    int* __restrict__ off, int* __restrict__ adj)
{
    __shared__ int hist[BNODES];     // becomes exclusive offsets, then cursors
    __shared__ int psum[256];
    __shared__ int adj_st[CAP];
    int tid = threadIdx.x;
    int b = blockIdx.x;
    int e0 = g_boff[b], e1 = g_boff[b + 1];
    int cnt = e1 - e0;
    int node_base = b * BNODES;

    hist[tid] = 0; hist[tid + 256] = 0;
    __syncthreads();
    for (int i = tid; i < cnt; i += 256)
        atomicAdd(&hist[staging[e0 + i] >> 18], 1);
    __syncthreads();

    int h0 = hist[2 * tid], h1 = hist[2 * tid + 1];
    psum[tid] = h0 + h1;
    __syncthreads();
    for (int d = 1; d < 256; d <<= 1) {
        int t = (tid >= d) ? psum[tid - d] : 0;
        __syncthreads();
        psum[tid] += t;
        __syncthreads();
    }
    int ex0 = psum[tid] - (h0 + h1);
    int ex1 = ex0 + h0;
    int n0 = node_base + 2 * tid;
    if (n0 < NN)     off[n0]     = e0 + ex0;
    if (n0 + 1 < NN) off[n0 + 1] = e0 + ex1;
    if (b == NB - 1 && tid == 0) off[NN] = e1;
    __syncthreads();
    hist[2 * tid] = ex0; hist[2 * tid + 1] = ex1;   // reuse as cursors
    __syncthreads();

    if (cnt <= CAP) {
        for (int i = tid; i < cnt; i += 256) {
            int v = staging[e0 + i];
            int p = atomicAdd(&hist[v >> 18], 1);
            adj_st[p] = v & 0x3FFFF;
        }
        __syncthreads();
        for (int i = tid; i < cnt; i += 256) adj[e0 + i] = adj_st[i];
    } else {  // statistically unreachable fallback
        for (int i = tid; i < cnt; i += 256) {
            int v = staging[e0 + i];
            int p = atomicAdd(&hist[v >> 18], 1);
            adj[e0 + p] = v & 0x3FFFF;
        }
    }
}

// ================= pull aggregation (one wave per node, writes mean) =================
__global__ __launch_bounds__(256) void pull_kernel(
    const int* __restrict__ off, const int* __restrict__ adj,
    const float* __restrict__ xu, const float* __restrict__ xi,
    float* __restrict__ agg_u, float* __restrict__ agg_i)
{
    int wid = (int)((blockIdx.x * 256 + threadIdx.x) >> 6);
    int lane = threadIdx.x & 63;
    if (wid >= NN) return;
    const float* table;
    float* out;
    int node;
    if (wid < NU) { node = wid;      table = xi; out = agg_u; }
    else          { node = wid - NU; table = xu; out = agg_i; }
    int beg = off[wid], end = off[wid + 1];
    float a0 = 0.f, a1 = 0.f, a2 = 0.f, a3 = 0.f;
    for (int k = beg; k < end; k += 64) {
        int nk = min(64, end - k);
        int nb = (lane < nk) ? adj[k + lane] : 0;
        int t = 0;
        for (; t + 4 <= nk; t += 4) {
            int n0 = __shfl(nb, t);
            int n1 = __shfl(nb, t + 1);
            int n2 = __shfl(nb, t + 2);
            int n3 = __shfl(nb, t + 3);
            a0 += table[(size_t)n0 * H + lane];
            a1 += table[(size_t)n1 * H + lane];
            a2 += table[(size_t)n2 * H + lane];
            a3 += table[(size_t)n3 * H + lane];
        }
        for (; t < nk; ++t)
            a0 += table[(size_t)__shfl(nb, t) * H + lane];
    }
    float s = (a0 + a1) + (a2 + a3);
    int deg = end - beg;
    out[(size_t)node * H + lane] = s / fmaxf((float)deg, 1.0f);
}

// ================= register-tiled node update =================
// relu(bn(agg_mean @ Wll + bll + x @ Wlr)); 64 nodes x 64 feats per block,
// thread = 4 nodes x 4 feats. n_nodes multiple of 64 (200000 = 3125*64).
__global__ __launch_bounds__(256) void update_kernel(
    const float* __restrict__ agg, const float* __restrict__ x_in,
    float* __restrict__ x_out,
    const float* __restrict__ Wll, const float* __restrict__ bll,
    const float* __restrict__ Wlr,
    const float* __restrict__ bng, const float* __restrict__ bnb,
    const float* __restrict__ bnm, const float* __restrict__ bnv)
{
    __shared__ float sWll[32][68];
    __shared__ float sWlr[32][68];
    __shared__ float sA[64][36];
    __shared__ float sX[64][36];
    int tid = threadIdx.x;
    int node0 = blockIdx.x * 64;
    int jt = (tid & 15) * 4;
    int nt = (tid >> 4) * 4;

    float4 b4 = *(const float4*)&bll[jt];
    float acc[4][4];
#pragma unroll
    for (int i = 0; i < 4; ++i) {
        acc[i][0] = b4.x; acc[i][1] = b4.y; acc[i][2] = b4.z; acc[i][3] = b4.w;
    }

    for (int kh = 0; kh < 2; ++kh) {
        int k0 = kh * 32;
        for (int idx = tid; idx < 32 * 64; idx += 256) {
            int kk = idx >> 6, j = idx & 63;
            sWll[kk][j] = Wll[(k0 + kk) * 64 + j];
            sWlr[kk][j] = Wlr[(k0 + kk) * 64 + j];
        }
        for (int idx = tid; idx < 64 * 32; idx += 256) {
            int r = idx >> 5, c = idx & 31;
            sA[r][c] = agg[(size_t)(node0 + r) * H + k0 + c];
            sX[r][c] = x_in[(size_t)(node0 + r) * H + k0 + c];
        }
        __syncthreads();
        for (int kk = 0; kk < 32; kk += 4) {
            float a[4][4], x[4][4];
#pragma unroll
            for (int i = 0; i < 4; ++i) {
                float4 t = *(const float4*)&sA[nt + i][kk];
                a[i][0] = t.x; a[i][1] = t.y; a[i][2] = t.z; a[i][3] = t.w;
                float4 u = *(const float4*)&sX[nt + i][kk];
                x[i][0] = u.x; x[i][1] = u.y; x[i][2] = u.z; x[i][3] = u.w;
            }
#pragma unroll
            for (int q = 0; q < 4; ++q) {
                float4 wl = *(const float4*)&sWll[kk + q][jt];
                float4 wr = *(const float4*)&sWlr[kk + q][jt];
                float wlv[4] = {wl.x, wl.y, wl.z, wl.w};
                float wrv[4] = {wr.x, wr.y, wr.z, wr.w};
#pragma unroll
                for (int i = 0; i < 4; ++i)
#pragma unroll
                    for (int j = 0; j < 4; ++j)
                        acc[i][j] += a[i][q] * wlv[j] + x[i][q] * wrv[j];
            }
        }
        __syncthreads();
    }

    float4 g4 = *(const float4*)&bng[jt];
    float4 bb4 = *(const float4*)&bnb[jt];
    float4 m4 = *(const float4*)&bnm[jt];
    float4 v4 = *(const float4*)&bnv[jt];
    float gv[4] = {g4.x, g4.y, g4.z, g4.w};
    float bv[4] = {bb4.x, bb4.y, bb4.z, bb4.w};
    float mv[4] = {m4.x, m4.y, m4.z, m4.w};
    float rv[4] = {rsqrtf(v4.x + EPSF), rsqrtf(v4.y + EPSF),
                   rsqrtf(v4.z + EPSF), rsqrtf(v4.w + EPSF)};
#pragma unroll
    for (int i = 0; i < 4; ++i) {
        int node = node0 + nt + i;
        float4 o;
        o.x = fmaxf((acc[i][0] - mv[0]) * rv[0] * gv[0] + bv[0], 0.f);
        o.y = fmaxf((acc[i][1] - mv[1]) * rv[1] * gv[1] + bv[1], 0.f);
        o.z = fmaxf((acc[i][2] - mv[2]) * rv[2] * gv[2] + bv[2], 0.f);
        o.w = fmaxf((acc[i][3] - mv[3]) * rv[3] * gv[3] + bv[3], 0.f);
        *(float4*)&x_out[(size_t)node * H + jt] = o;
    }
}

// ================= MLP head (register-tiled fc1, LDS fc2) =================
__global__ __launch_bounds__(256) void mlp_kernel(
    const int* __restrict__ eli,
    const float* __restrict__ xu, const float* __restrict__ xi,
    const float* __restrict__ fc1w, const float* __restrict__ fc1b,
    const float* __restrict__ fc2w, const float* __restrict__ fc2b,
    float* __restrict__ out, int n)
{
    __shared__ float sW[32][68];
    __shared__ float sA[64][36];
    __shared__ float sH[64][68];
    __shared__ int   sid[128];
    __shared__ float sW2[256];
    int tid = threadIdx.x;
    int p0 = blockIdx.x * 64;
    if (tid < 128) {
        int p = p0 + (tid & 63);
        int side = tid >> 6;
        sid[tid] = (p < n) ? eli[side * NP + p] : -1;
    }
    sW2[tid] = fc2w[tid];
    __syncthreads();

    int jt = (tid & 15) * 4;
    int pt = (tid >> 4) * 4;
    float4 b4 = *(const float4*)&fc1b[jt];
    float acc[4][4];
#pragma unroll
    for (int i = 0; i < 4; ++i) {
        acc[i][0] = b4.x; acc[i][1] = b4.y; acc[i][2] = b4.z; acc[i][3] = b4.w;
    }

    for (int ch = 0; ch < 4; ++ch) {
        int k0 = ch * 32;
        const float* tab = (ch < 2) ? xu : xi;
        int idbase = (ch < 2) ? 0 : 64;
        int koff = (ch & 1) * 32;
        for (int idx = tid; idx < 64 * 32; idx += 256) {
            int r = idx >> 5, c = idx & 31;
            int id = sid[idbase + r];
            sA[r][c] = (id >= 0) ? tab[(size_t)id * H + koff + c] : 0.f;
        }
        for (int idx = tid; idx < 32 * 64; idx += 256) {
            int kk = idx >> 6, j = idx & 63;
            sW[kk][j] = fc1w[(k0 + kk) * 64 + j];
        }
        __syncthreads();
        for (int kk = 0; kk < 32; kk += 4) {
            float a[4][4];
#pragma unroll
            for (int i = 0; i < 4; ++i) {
                float4 t = *(const float4*)&sA[pt + i][kk];
                a[i][0] = t.x; a[i][1] = t.y; a[i][2] = t.z; a[i][3] = t.w;
            }
#pragma unroll
            for (int q = 0; q < 4; ++q) {
                float4 w = *(const float4*)&sW[kk + q][jt];
                float wv[4] = {w.x, w.y, w.z, w.w};
#pragma unroll
                for (int i = 0; i < 4; ++i)
#pragma unroll
                    for (int j = 0; j < 4; ++j)
                        acc[i][j] += a[i][q] * wv[j];
            }
        }
        __syncthreads();
    }

#pragma unroll
    for (int i = 0; i < 4; ++i)
#pragma unroll
        for (int j = 0; j < 4; ++j)
            sH[pt + i][jt + j] = fmaxf(acc[i][j], 0.f);
    __syncthreads();

    int pp = tid >> 2, c = tid & 3;
    float o = 0.f;
#pragma unroll
    for (int j = 0; j < 64; ++j) o += sH[pp][j] * sW2[j * 4 + c];
    int p = p0 + pp;
    if (p < n) out[(size_t)p * 4 + c] = o + fc2b[c];
}

extern "C" void kernel_launch(void* const* d_in, const int* in_sizes, int n_in,
                              void* d_out, int out_size, void* d_ws, size_t ws_size,
                              hipStream_t stream) {
    const int*   edge_index = (const int*)d_in[0];
    const int*   eli        = (const int*)d_in[1];
    const float* user_emb   = (const float*)d_in[2];
    const float* item_emb   = (const float*)d_in[3];
    const float* u_ll_w     = (const float*)d_in[4];
    const float* u_ll_b     = (const float*)d_in[5];
    const float* u_lr_w     = (const float*)d_in[6];
    const float* i_ll_w     = (const float*)d_in[7];
    const float* i_ll_b     = (const float*)d_in[8];
    const float* i_lr_w     = (const float*)d_in[9];
    const float* u_bn_g     = (const float*)d_in[10];
    const float* u_bn_b     = (const float*)d_in[11];
    const float* u_bn_m     = (const float*)d_in[12];
    const float* u_bn_v     = (const float*)d_in[13];
    const float* i_bn_g     = (const float*)d_in[14];
    const float* i_bn_b     = (const float*)d_in[15];
    const float* i_bn_m     = (const float*)d_in[16];
    const float* i_bn_v     = (const float*)d_in[17];
    const float* fc1_w      = (const float*)d_in[18];
    const float* fc1_b      = (const float*)d_in[19];
    const float* fc2_w      = (const float*)d_in[20];
    const float* fc2_b      = (const float*)d_in[21];
    float* out = (float*)d_out;

    const int* src = edge_index;
    const int* dst = edge_index + NE;

    // workspace layout
    char* w = (char*)d_ws;
    float* bufA_u = (float*)w;  w += (size_t)NU * H * 4;
    float* bufA_i = (float*)w;  w += (size_t)NI * H * 4;
    float* bufB_u = (float*)w;  w += (size_t)NU * H * 4;
    float* bufB_i = (float*)w;  w += (size_t)NI * H * 4;
    int* adj    = (int*)w;      w += (size_t)2 * NE * 4;
    int* off    = (int*)w;      w += (size_t)(NN + 1) * 4;
    int* g_bcnt = (int*)w;      w += (size_t)NB * 4;
    int* g_boff = (int*)w;      w += (size_t)(NB + 1) * 4;
    // staging (8M ints = 32 MB) aliases bufB_u (51.2 MB); blkhist (1.6 MB)
    // aliases bufB_i. CSR build fully completes before layer 1 writes bufB.
    int* staging = (int*)bufB_u;
    int* blkhist = (int*)bufB_i;

    // ---- CSR build (no global atomics, no memsets) ----
    part1_kernel<<<PBLOCKS, 256, 0, stream>>>(src, dst, blkhist);
    colscan_kernel<<<NB, 256, 0, stream>>>(blkhist, g_bcnt);
    bucket_scan_kernel<<<1, 1024, 0, stream>>>(g_bcnt, g_boff);
    part2_kernel<<<PBLOCKS, 256, 0, stream>>>(src, dst, g_boff, blkhist, staging);
    bucket_fill_kernel<<<NB, 256, 0, stream>>>(g_boff, staging, off, adj);

    const int pull_blocks = NN / 4;

    // ---- layer 0 ----
    pull_kernel<<<pull_blocks, 256, 0, stream>>>(
        off, adj, user_emb, item_emb, bufA_u, bufA_i);
    update_kernel<<<NU / 64, 256, 0, stream>>>(
        bufA_u, user_emb, bufA_u,
        u_ll_w, u_ll_b, u_lr_w, u_bn_g, u_bn_b, u_bn_m, u_bn_v);
    update_kernel<<<NI / 64, 256, 0, stream>>>(
        bufA_i, item_emb, bufA_i,
        i_ll_w, i_ll_b, i_lr_w, i_bn_g, i_bn_b, i_bn_m, i_bn_v);

    // ---- layer 1 ----
    pull_kernel<<<pull_blocks, 256, 0, stream>>>(
        off, adj, bufA_u, bufA_i, bufB_u, bufB_i);
    update_kernel<<<NU / 64, 256, 0, stream>>>(
        bufB_u, bufA_u, bufB_u,
        u_ll_w + H * H, u_ll_b + H, u_lr_w + H * H,
        u_bn_g + H, u_bn_b + H, u_bn_m + H, u_bn_v + H);
    update_kernel<<<NI / 64, 256, 0, stream>>>(
        bufB_i, bufA_i, bufB_i,
        i_ll_w + H * H, i_ll_b + H, i_lr_w + H * H,
        i_bn_g + H, i_bn_b + H, i_bn_m + H, i_bn_v + H);

    // ---- MLP head ----
    mlp_kernel<<<(NP + 63) / 64, 256, 0, stream>>>(
        eli, bufB_u, bufB_i, fc1_w, fc1_b, fc2_w, fc2_b, out, NP);
}

// Round 7
// 1020.432 us; speedup vs baseline: 2.6131x; 1.1108x over previous
//
#include <hip/hip_runtime.h>

#define NU 200000
#define NI 200000
#define NN 400000          // NU + NI (unified node space: users 0..NU-1, items NU..NN-1)
#define H 64
#define NE 4000000
#define NP 100000
#define EPSF 1e-5f

#define BSH 9              // nodes per bucket = 512
#define BNODES 512
#define NB ((NN + BNODES - 1) / BNODES)   // 782 buckets
#define CAP 15104          // LDS adj staging entries per bucket (mean 10240, sigma ~101)

#define PBLOCKS 512                          // partition blocks
#define EPB ((NE + PBLOCKS - 1) / PBLOCKS)   // 7813 edges per block slice

typedef unsigned short u16;

__device__ __forceinline__ u16 f2bf(float f) {
    unsigned int b = __float_as_uint(f);
    b += 0x7FFFu + ((b >> 16) & 1u);     // round-to-nearest-even
    return (u16)(b >> 16);
}

// ================= CSR build (two-phase, LDS-atomic-only) =================

__global__ __launch_bounds__(256) void part1_kernel(
    const int* __restrict__ src, const int* __restrict__ dst,
    int* __restrict__ blkhist)
{
    __shared__ int hist[NB];
    int tid = threadIdx.x, blk = blockIdx.x;
    for (int i = tid; i < NB; i += 256) hist[i] = 0;
    __syncthreads();
    int e0 = blk * EPB, e1 = min(NE, e0 + EPB);
    for (int e = e0 + tid; e < e1; e += 256) {
        atomicAdd(&hist[src[e] >> BSH], 1);
        atomicAdd(&hist[(NU + dst[e]) >> BSH], 1);
    }
    __syncthreads();
    for (int i = tid; i < NB; i += 256)
        blkhist[(size_t)i * PBLOCKS + blk] = hist[i];
}

__global__ __launch_bounds__(256) void colscan_kernel(
    int* __restrict__ blkhist, int* __restrict__ g_bcnt)
{
    __shared__ int s[256];
    int b = blockIdx.x, tid = threadIdx.x;
    int* col = blkhist + (size_t)b * PBLOCKS;
    int v0 = col[2 * tid], v1 = col[2 * tid + 1];
    int ps = v0 + v1;
    s[tid] = ps;
    __syncthreads();
    for (int d = 1; d < 256; d <<= 1) {
        int t = (tid >= d) ? s[tid - d] : 0;
        __syncthreads();
        s[tid] += t;
        __syncthreads();
    }
    int ex = s[tid] - ps;   // exclusive over pairs
    col[2 * tid] = ex;
    col[2 * tid + 1] = ex + v0;
    if (tid == 255) g_bcnt[b] = s[255];
}

__global__ __launch_bounds__(1024) void bucket_scan_kernel(
    const int* __restrict__ g_bcnt, int* __restrict__ g_boff)
{
    __shared__ int s[1024];
    int tid = threadIdx.x;
    int v = (tid < NB) ? g_bcnt[tid] : 0;
    s[tid] = v;
    __syncthreads();
    for (int d = 1; d < 1024; d <<= 1) {
        int t = (tid >= d) ? s[tid - d] : 0;
        __syncthreads();
        s[tid] += t;
        __syncthreads();
    }
    if (tid < NB) g_boff[tid + 1] = s[tid];
    if (tid == 0) g_boff[0] = 0;
}

// entry = (local_node << 18) | neighbor   (local<512 -> 9 bits, nbr<200000 -> 18 bits)
__global__ __launch_bounds__(256) void part2_kernel(
    const int* __restrict__ src, const int* __restrict__ dst,
    const int* __restrict__ g_boff, const int* __restrict__ blkhist,
    int* __restrict__ staging)
{
    __shared__ int cur[NB];
    int tid = threadIdx.x, blk = blockIdx.x;
    for (int i = tid; i < NB; i += 256)
        cur[i] = g_boff[i] + blkhist[(size_t)i * PBLOCKS + blk];
    __syncthreads();
    int e0 = blk * EPB, e1 = min(NE, e0 + EPB);
    for (int e = e0 + tid; e < e1; e += 256) {
        int s = src[e], d = dst[e];
        int p1 = atomicAdd(&cur[s >> BSH], 1);
        staging[p1] = ((s & (BNODES - 1)) << 18) | d;
        int gn = NU + d;
        int p2 = atomicAdd(&cur[gn >> BSH], 1);
        staging[p2] = ((gn & (BNODES - 1)) << 18) | s;
    }
}

__global__ __launch_bounds__(256) void bucket_fill_kernel(
    const int* __restrict__ g_boff, const int* __restrict__ staging,
    int* __restrict__ off, int* __restrict__ adj)
{
    __shared__ int hist[BNODES];     // becomes exclusive offsets, then cursors
    __shared__ int psum[256];
    __shared__ int adj_st[CAP];
    int tid = threadIdx.x;
    int b = blockIdx.x;
    int e0 = g_boff[b], e1 = g_boff[b + 1];
    int cnt = e1 - e0;
    int node_base = b * BNODES;

    hist[tid] = 0; hist[tid + 256] = 0;
    __syncthreads();
    for (int i = tid; i < cnt; i += 256)
        atomicAdd(&hist[staging[e0 + i] >> 18], 1);
    __syncthreads();

    int h0 = hist[2 * tid], h1 = hist[2 * tid + 1];
    psum[tid] = h0 + h1;
    __syncthreads();
    for (int d = 1; d < 256; d <<= 1) {
        int t = (tid >= d) ? psum[tid - d] : 0;
        __syncthreads();
        psum[tid] += t;
        __syncthreads();
    }
    int ex0 = psum[tid] - (h0 + h1);
    int ex1 = ex0 + h0;
    int n0 = node_base + 2 * tid;
    if (n0 < NN)     off[n0]     = e0 + ex0;
    if (n0 + 1 < NN) off[n0 + 1] = e0 + ex1;
    if (b == NB - 1 && tid == 0) off[NN] = e1;
    __syncthreads();
    hist[2 * tid] = ex0; hist[2 * tid + 1] = ex1;   // reuse as cursors
    __syncthreads();

    if (cnt <= CAP) {
        for (int i = tid; i < cnt; i += 256) {
            int v = staging[e0 + i];
            int p = atomicAdd(&hist[v >> 18], 1);
            adj_st[p] = v & 0x3FFFF;
        }
        __syncthreads();
        for (int i = tid; i < cnt; i += 256) adj[e0 + i] = adj_st[i];
    } else {  // statistically unreachable fallback
        for (int i = tid; i < cnt; i += 256) {
            int v = staging[e0 + i];
            int p = atomicAdd(&hist[v >> 18], 1);
            adj[e0 + p] = v & 0x3FFFF;
        }
    }
}

// ================= f32 -> bf16 table conversion =================
__global__ __launch_bounds__(256) void cvt_kernel(
    const float4* __restrict__ in, ushort4* __restrict__ out, int n4)
{
    int i = blockIdx.x * 256 + threadIdx.x;
    if (i >= n4) return;
    float4 v = in[i];
    ushort4 h;
    h.x = f2bf(v.x); h.y = f2bf(v.y); h.z = f2bf(v.z); h.w = f2bf(v.w);
    out[i] = h;
}

// ================= pull aggregation (one wave per node, bf16 in, bf16 mean out) ====
// Lanes 0-31 fetch neighbor A, lanes 32-63 fetch neighbor B (128 B rows);
// each lane holds feature pair (2*hl, 2*hl+1); xor-32 combine at the end.
__global__ __launch_bounds__(256) void pull_kernel(
    const int* __restrict__ off, const int* __restrict__ adj,
    const u16* __restrict__ xu16, const u16* __restrict__ xi16,
    u16* __restrict__ agg_u, u16* __restrict__ agg_i)
{
    int wid = (int)((blockIdx.x * 256 + threadIdx.x) >> 6);
    int lane = threadIdx.x & 63;
    if (wid >= NN) return;
    const u16* table;
    u16* out;
    int node;
    if (wid < NU) { node = wid;      table = xi16; out = agg_u; }
    else          { node = wid - NU; table = xu16; out = agg_i; }
    int beg = off[wid], end = off[wid + 1];
    int half = lane >> 5;
    int hl = lane & 31;
    float2 a0 = {0.f, 0.f}, a1 = {0.f, 0.f}, a2 = {0.f, 0.f}, a3 = {0.f, 0.f};
    for (int k = beg; k < end; k += 64) {
        int nk = min(64, end - k);
        int nb = (lane < nk) ? adj[k + lane] : 0;
        int t = 0;
        for (; t + 8 <= nk; t += 8) {
            int n0 = __shfl(nb, t + 0 + half);
            int n1 = __shfl(nb, t + 2 + half);
            int n2 = __shfl(nb, t + 4 + half);
            int n3 = __shfl(nb, t + 6 + half);
            unsigned int w0 = *(const unsigned int*)&table[(size_t)n0 * H + hl * 2];
            unsigned int w1 = *(const unsigned int*)&table[(size_t)n1 * H + hl * 2];
            unsigned int w2 = *(const unsigned int*)&table[(size_t)n2 * H + hl * 2];
            unsigned int w3 = *(const unsigned int*)&table[(size_t)n3 * H + hl * 2];
            a0.x += __uint_as_float(w0 << 16); a0.y += __uint_as_float(w0 & 0xFFFF0000u);
            a1.x += __uint_as_float(w1 << 16); a1.y += __uint_as_float(w1 & 0xFFFF0000u);
            a2.x += __uint_as_float(w2 << 16); a2.y += __uint_as_float(w2 & 0xFFFF0000u);
            a3.x += __uint_as_float(w3 << 16); a3.y += __uint_as_float(w3 & 0xFFFF0000u);
        }
        for (; t < nk; t += 2) {
            int idx = t + half;
            bool valid = idx < nk;
            int n = __shfl(nb, valid ? idx : t);
            unsigned int w = *(const unsigned int*)&table[(size_t)n * H + hl * 2];
            if (valid) {
                a0.x += __uint_as_float(w << 16);
                a0.y += __uint_as_float(w & 0xFFFF0000u);
            }
        }
    }
    float sx = (a0.x + a1.x) + (a2.x + a3.x);
    float sy = (a0.y + a1.y) + (a2.y + a3.y);
    sx += __shfl_xor(sx, 32);
    sy += __shfl_xor(sy, 32);
    if (half == 0) {
        int deg = end - beg;
        float inv = 1.0f / fmaxf((float)deg, 1.0f);
        unsigned int packed = ((unsigned int)f2bf(sy * inv) << 16) | f2bf(sx * inv);
        *(unsigned int*)&out[(size_t)node * H + hl * 2] = packed;
    }
}

// ================= register-tiled node update =================
// relu(bn(agg_mean(bf16) @ Wll + bll + x_in(f32) @ Wlr)); 64 nodes x 64 feats
// per block, thread = 4 nodes x 4 feats. Writes f32 x_out; optional bf16 copy.
// x_out may alias x_in (rows staged to LDS before write; blocks own disjoint rows).
__global__ __launch_bounds__(256) void update_kernel(
    const u16* __restrict__ agg16, const float* __restrict__ x_in,
    float* __restrict__ x_out, u16* __restrict__ x16_out,
    const float* __restrict__ Wll, const float* __restrict__ bll,
    const float* __restrict__ Wlr,
    const float* __restrict__ bng, const float* __restrict__ bnb,
    const float* __restrict__ bnm, const float* __restrict__ bnv)
{
    __shared__ float sWll[32][68];
    __shared__ float sWlr[32][68];
    __shared__ float sA[64][36];
    __shared__ float sX[64][36];
    int tid = threadIdx.x;
    int node0 = blockIdx.x * 64;
    int jt = (tid & 15) * 4;
    int nt = (tid >> 4) * 4;

    float4 b4 = *(const float4*)&bll[jt];
    float acc[4][4];
#pragma unroll
    for (int i = 0; i < 4; ++i) {
        acc[i][0] = b4.x; acc[i][1] = b4.y; acc[i][2] = b4.z; acc[i][3] = b4.w;
    }

    for (int kh = 0; kh < 2; ++kh) {
        int k0 = kh * 32;
        for (int idx = tid; idx < 32 * 64; idx += 256) {
            int kk = idx >> 6, j = idx & 63;
            sWll[kk][j] = Wll[(k0 + kk) * 64 + j];
            sWlr[kk][j] = Wlr[(k0 + kk) * 64 + j];
        }
        for (int idx = tid; idx < 64 * 16; idx += 256) {   // bf16 agg: uint pairs
            int r = idx >> 4, cp = idx & 15;
            unsigned int wv = *(const unsigned int*)&agg16[(size_t)(node0 + r) * H + k0 + cp * 2];
            sA[r][cp * 2]     = __uint_as_float(wv << 16);
            sA[r][cp * 2 + 1] = __uint_as_float(wv & 0xFFFF0000u);
        }
        for (int idx = tid; idx < 64 * 32; idx += 256) {
            int r = idx >> 5, c = idx & 31;
            sX[r][c] = x_in[(size_t)(node0 + r) * H + k0 + c];
        }
        __syncthreads();
        for (int kk = 0; kk < 32; kk += 4) {
            float a[4][4], x[4][4];
#pragma unroll
            for (int i = 0; i < 4; ++i) {
                float4 t = *(const float4*)&sA[nt + i][kk];
                a[i][0] = t.x; a[i][1] = t.y; a[i][2] = t.z; a[i][3] = t.w;
                float4 u = *(const float4*)&sX[nt + i][kk];
                x[i][0] = u.x; x[i][1] = u.y; x[i][2] = u.z; x[i][3] = u.w;
            }
#pragma unroll
            for (int q = 0; q < 4; ++q) {
                float4 wl = *(const float4*)&sWll[kk + q][jt];
                float4 wr = *(const float4*)&sWlr[kk + q][jt];
                float wlv[4] = {wl.x, wl.y, wl.z, wl.w};
                float wrv[4] = {wr.x, wr.y, wr.z, wr.w};
#pragma unroll
                for (int i = 0; i < 4; ++i)
#pragma unroll
                    for (int j = 0; j < 4; ++j)
                        acc[i][j] += a[i][q] * wlv[j] + x[i][q] * wrv[j];
            }
        }
        __syncthreads();
    }

    float4 g4 = *(const float4*)&bng[jt];
    float4 bb4 = *(const float4*)&bnb[jt];
    float4 m4 = *(const float4*)&bnm[jt];
    float4 v4 = *(const float4*)&bnv[jt];
    float gv[4] = {g4.x, g4.y, g4.z, g4.w};
    float bv[4] = {bb4.x, bb4.y, bb4.z, bb4.w};
    float mv[4] = {m4.x, m4.y, m4.z, m4.w};
    float rv[4] = {rsqrtf(v4.x + EPSF), rsqrtf(v4.y + EPSF),
                   rsqrtf(v4.z + EPSF), rsqrtf(v4.w + EPSF)};
#pragma unroll
    for (int i = 0; i < 4; ++i) {
        int node = node0 + nt + i;
        float4 o;
        o.x = fmaxf((acc[i][0] - mv[0]) * rv[0] * gv[0] + bv[0], 0.f);
        o.y = fmaxf((acc[i][1] - mv[1]) * rv[1] * gv[1] + bv[1], 0.f);
        o.z = fmaxf((acc[i][2] - mv[2]) * rv[2] * gv[2] + bv[2], 0.f);
        o.w = fmaxf((acc[i][3] - mv[3]) * rv[3] * gv[3] + bv[3], 0.f);
        *(float4*)&x_out[(size_t)node * H + jt] = o;
        if (x16_out) {
            ushort4 h;
            h.x = f2bf(o.x); h.y = f2bf(o.y); h.z = f2bf(o.z); h.w = f2bf(o.w);
            *(ushort4*)&x16_out[(size_t)node * H + jt] = h;
        }
    }
}

// ================= MLP head (register-tiled fc1, LDS fc2) =================
__global__ __launch_bounds__(256) void mlp_kernel(
    const int* __restrict__ eli,
    const float* __restrict__ xu, const float* __restrict__ xi,
    const float* __restrict__ fc1w, const float* __restrict__ fc1b,
    const float* __restrict__ fc2w, const float* __restrict__ fc2b,
    float* __restrict__ out, int n)
{
    __shared__ float sW[32][68];
    __shared__ float sA[64][36];
    __shared__ float sH[64][68];
    __shared__ int   sid[128];
    __shared__ float sW2[256];
    int tid = threadIdx.x;
    int p0 = blockIdx.x * 64;
    if (tid < 128) {
        int p = p0 + (tid & 63);
        int side = tid >> 6;
        sid[tid] = (p < n) ? eli[side * NP + p] : -1;
    }
    sW2[tid] = fc2w[tid];
    __syncthreads();

    int jt = (tid & 15) * 4;
    int pt = (tid >> 4) * 4;
    float4 b4 = *(const float4*)&fc1b[jt];
    float acc[4][4];
#pragma unroll
    for (int i = 0; i < 4; ++i) {
        acc[i][0] = b4.x; acc[i][1] = b4.y; acc[i][2] = b4.z; acc[i][3] = b4.w;
    }

    for (int ch = 0; ch < 4; ++ch) {
        int k0 = ch * 32;
        const float* tab = (ch < 2) ? xu : xi;
        int idbase = (ch < 2) ? 0 : 64;
        int koff = (ch & 1) * 32;
        for (int idx = tid; idx < 64 * 32; idx += 256) {
            int r = idx >> 5, c = idx & 31;
            int id = sid[idbase + r];
            sA[r][c] = (id >= 0) ? tab[(size_t)id * H + koff + c] : 0.f;
        }
        for (int idx = tid; idx < 32 * 64; idx += 256) {
            int kk = idx >> 6, j = idx & 63;
            sW[kk][j] = fc1w[(k0 + kk) * 64 + j];
        }
        __syncthreads();
        for (int kk = 0; kk < 32; kk += 4) {
            float a[4][4];
#pragma unroll
            for (int i = 0; i < 4; ++i) {
                float4 t = *(const float4*)&sA[pt + i][kk];
                a[i][0] = t.x; a[i][1] = t.y; a[i][2] = t.z; a[i][3] = t.w;
            }
#pragma unroll
            for (int q = 0; q < 4; ++q) {
                float4 w = *(const float4*)&sW[kk + q][jt];
                float wv[4] = {w.x, w.y, w.z, w.w};
#pragma unroll
                for (int i = 0; i < 4; ++i)
#pragma unroll
                    for (int j = 0; j < 4; ++j)
                        acc[i][j] += a[i][q] * wv[j];
            }
        }
        __syncthreads();
    }

#pragma unroll
    for (int i = 0; i < 4; ++i)
#pragma unroll
        for (int j = 0; j < 4; ++j)
            sH[pt + i][jt + j] = fmaxf(acc[i][j], 0.f);
    __syncthreads();

    int pp = tid >> 2, c = tid & 3;
    float o = 0.f;
#pragma unroll
    for (int j = 0; j < 64; ++j) o += sH[pp][j] * sW2[j * 4 + c];
    int p = p0 + pp;
    if (p < n) out[(size_t)p * 4 + c] = o + fc2b[c];
}

extern "C" void kernel_launch(void* const* d_in, const int* in_sizes, int n_in,
                              void* d_out, int out_size, void* d_ws, size_t ws_size,
                              hipStream_t stream) {
    const int*   edge_index = (const int*)d_in[0];
    const int*   eli        = (const int*)d_in[1];
    const float* user_emb   = (const float*)d_in[2];
    const float* item_emb   = (const float*)d_in[3];
    const float* u_ll_w     = (const float*)d_in[4];
    const float* u_ll_b     = (const float*)d_in[5];
    const float* u_lr_w     = (const float*)d_in[6];
    const float* i_ll_w     = (const float*)d_in[7];
    const float* i_ll_b     = (const float*)d_in[8];
    const float* i_lr_w     = (const float*)d_in[9];
    const float* u_bn_g     = (const float*)d_in[10];
    const float* u_bn_b     = (const float*)d_in[11];
    const float* u_bn_m     = (const float*)d_in[12];
    const float* u_bn_v     = (const float*)d_in[13];
    const float* i_bn_g     = (const float*)d_in[14];
    const float* i_bn_b     = (const float*)d_in[15];
    const float* i_bn_m     = (const float*)d_in[16];
    const float* i_bn_v     = (const float*)d_in[17];
    const float* fc1_w      = (const float*)d_in[18];
    const float* fc1_b      = (const float*)d_in[19];
    const float* fc2_w      = (const float*)d_in[20];
    const float* fc2_b      = (const float*)d_in[21];
    float* out = (float*)d_out;

    const int* src = edge_index;
    const int* dst = edge_index + NE;

    // ---- workspace layout: total 238.4 MB (== round-4's proven footprint;
    //      round-5's 289.6 MB appears to have overrun ws_size) ----
    char* w = (char*)d_ws;
    float* featU = (float*)w;   w += (size_t)NU * H * 4;   // F2_u: L0 feats -> final feats
    float* featI = (float*)w;   w += (size_t)NI * H * 4;   // F2_i
    u16*   f1    = (u16*)w;     w += (size_t)4 * NU * H * 2;  // 4 bf16 slots of 25.6 MB
    int* adj    = (int*)w;      w += (size_t)2 * NE * 4;
    int* off    = (int*)w;      w += (size_t)(NN + 1) * 4;
    int* g_bcnt = (int*)w;      w += (size_t)NB * 4;
    int* g_boff = (int*)w;      w += (size_t)(NB + 1) * 4;

    // F1 slot timeline (each slot NU*H bf16 = 25.6 MB):
    //   slots 0-1: staging (32 MB, CSR)  ->  emb16_u/emb16_i  ->  xA16_u/xA16_i
    //   slots 2-3: agg0_u/agg0_i (L0)    ->  agg1_u/agg1_i (L1)
    int* staging  = (int*)f1;                       // dead before cvt
    u16* emb16_u  = f1;
    u16* emb16_i  = f1 + (size_t)NU * H;
    u16* xA16_u   = f1;                             // reuses slots 0-1 after L0 pull
    u16* xA16_i   = f1 + (size_t)NU * H;
    u16* agg16_u  = f1 + (size_t)2 * NU * H;
    u16* agg16_i  = f1 + (size_t)3 * NU * H;
    int* blkhist  = (int*)featU;                    // 1.6 MB, dead before L0 update

    // ---- CSR build (no global atomics, no memsets) ----
    part1_kernel<<<PBLOCKS, 256, 0, stream>>>(src, dst, blkhist);
    colscan_kernel<<<NB, 256, 0, stream>>>(blkhist, g_bcnt);
    bucket_scan_kernel<<<1, 1024, 0, stream>>>(g_bcnt, g_boff);
    part2_kernel<<<PBLOCKS, 256, 0, stream>>>(src, dst, g_boff, blkhist, staging);
    bucket_fill_kernel<<<NB, 256, 0, stream>>>(g_boff, staging, off, adj);

    // ---- bf16 copies of the embeddings (staging dead now) ----
    const int n4 = NU * H / 4;
    cvt_kernel<<<(n4 + 255) / 256, 256, 0, stream>>>(
        (const float4*)user_emb, (ushort4*)emb16_u, n4);
    cvt_kernel<<<(n4 + 255) / 256, 256, 0, stream>>>(
        (const float4*)item_emb, (ushort4*)emb16_i, n4);

    const int pull_blocks = NN / 4;

    // ---- layer 0 ----
    pull_kernel<<<pull_blocks, 256, 0, stream>>>(
        off, adj, emb16_u, emb16_i, agg16_u, agg16_i);
    update_kernel<<<NU / 64, 256, 0, stream>>>(
        agg16_u, user_emb, featU, xA16_u,
        u_ll_w, u_ll_b, u_lr_w, u_bn_g, u_bn_b, u_bn_m, u_bn_v);
    update_kernel<<<NI / 64, 256, 0, stream>>>(
        agg16_i, item_emb, featI, xA16_i,
        i_ll_w, i_ll_b, i_lr_w, i_bn_g, i_bn_b, i_bn_m, i_bn_v);

    // ---- layer 1 (gathers bf16 L0 features; self path reads f32 feats) ----
    pull_kernel<<<pull_blocks, 256, 0, stream>>>(
        off, adj, xA16_u, xA16_i, agg16_u, agg16_i);
    update_kernel<<<NU / 64, 256, 0, stream>>>(
        agg16_u, featU, featU, (u16*)nullptr,
        u_ll_w + H * H, u_ll_b + H, u_lr_w + H * H,
        u_bn_g + H, u_bn_b + H, u_bn_m + H, u_bn_v + H);
    update_kernel<<<NI / 64, 256, 0, stream>>>(
        agg16_i, featI, featI, (u16*)nullptr,
        i_ll_w + H * H, i_ll_b + H, i_lr_w + H * H,
        i_bn_g + H, i_bn_b + H, i_bn_m + H, i_bn_v + H);

    // ---- MLP head ----
    mlp_kernel<<<(NP + 63) / 64, 256, 0, stream>>>(
        eli, featU, featI, fc1_w, fc1_b, fc2_w, fc2_b, out, NP);
}

// Round 8
// 934.909 us; speedup vs baseline: 2.8521x; 1.0915x over previous
//
#include <hip/hip_runtime.h>

#define NU 200000
#define NI 200000
#define NN 400000          // NU + NI (unified node space: users 0..NU-1, items NU..NN-1)
#define H 64
#define NE 4000000
#define NP 100000
#define EPSF 1e-5f

#define BSH 9              // nodes per bucket = 512
#define BNODES 512
#define NB ((NN + BNODES - 1) / BNODES)   // 782 buckets
#define CAP 15104          // LDS adj staging entries per bucket (mean 10240, sigma ~101)

#define PBLOCKS 512                          // partition blocks
#define EPB ((NE + PBLOCKS - 1) / PBLOCKS)   // 7813 edges per block slice

typedef unsigned short u16;

__device__ __forceinline__ u16 f2bf(float f) {
    unsigned int b = __float_as_uint(f);
    b += 0x7FFFu + ((b >> 16) & 1u);     // round-to-nearest-even
    return (u16)(b >> 16);
}

// ================= CSR build (two-phase, LDS-atomic-only) =================

__global__ __launch_bounds__(256) void part1_kernel(
    const int* __restrict__ src, const int* __restrict__ dst,
    int* __restrict__ blkhist)
{
    __shared__ int hist[NB];
    int tid = threadIdx.x, blk = blockIdx.x;
    for (int i = tid; i < NB; i += 256) hist[i] = 0;
    __syncthreads();
    int e0 = blk * EPB, e1 = min(NE, e0 + EPB);
    for (int e = e0 + tid; e < e1; e += 256) {
        atomicAdd(&hist[src[e] >> BSH], 1);
        atomicAdd(&hist[(NU + dst[e]) >> BSH], 1);
    }
    __syncthreads();
    for (int i = tid; i < NB; i += 256)
        blkhist[(size_t)i * PBLOCKS + blk] = hist[i];
}

__global__ __launch_bounds__(256) void colscan_kernel(
    int* __restrict__ blkhist, int* __restrict__ g_bcnt)
{
    __shared__ int s[256];
    int b = blockIdx.x, tid = threadIdx.x;
    int* col = blkhist + (size_t)b * PBLOCKS;
    int v0 = col[2 * tid], v1 = col[2 * tid + 1];
    int ps = v0 + v1;
    s[tid] = ps;
    __syncthreads();
    for (int d = 1; d < 256; d <<= 1) {
        int t = (tid >= d) ? s[tid - d] : 0;
        __syncthreads();
        s[tid] += t;
        __syncthreads();
    }
    int ex = s[tid] - ps;   // exclusive over pairs
    col[2 * tid] = ex;
    col[2 * tid + 1] = ex + v0;
    if (tid == 255) g_bcnt[b] = s[255];
}

__global__ __launch_bounds__(1024) void bucket_scan_kernel(
    const int* __restrict__ g_bcnt, int* __restrict__ g_boff)
{
    __shared__ int s[1024];
    int tid = threadIdx.x;
    int v = (tid < NB) ? g_bcnt[tid] : 0;
    s[tid] = v;
    __syncthreads();
    for (int d = 1; d < 1024; d <<= 1) {
        int t = (tid >= d) ? s[tid - d] : 0;
        __syncthreads();
        s[tid] += t;
        __syncthreads();
    }
    if (tid < NB) g_boff[tid + 1] = s[tid];
    if (tid == 0) g_boff[0] = 0;
}

// entry = (local_node << 18) | neighbor   (local<512 -> 9 bits, nbr<200000 -> 18 bits)
__global__ __launch_bounds__(256) void part2_kernel(
    const int* __restrict__ src, const int* __restrict__ dst,
    const int* __restrict__ g_boff, const int* __restrict__ blkhist,
    int* __restrict__ staging)
{
    __shared__ int cur[NB];
    int tid = threadIdx.x, blk = blockIdx.x;
    for (int i = tid; i < NB; i += 256)
        cur[i] = g_boff[i] + blkhist[(size_t)i * PBLOCKS + blk];
    __syncthreads();
    int e0 = blk * EPB, e1 = min(NE, e0 + EPB);
    for (int e = e0 + tid; e < e1; e += 256) {
        int s = src[e], d = dst[e];
        int p1 = atomicAdd(&cur[s >> BSH], 1);
        staging[p1] = ((s & (BNODES - 1)) << 18) | d;
        int gn = NU + d;
        int p2 = atomicAdd(&cur[gn >> BSH], 1);
        staging[p2] = ((gn & (BNODES - 1)) << 18) | s;
    }
}

__global__ __launch_bounds__(256) void bucket_fill_kernel(
    const int* __restrict__ g_boff, const int* __restrict__ staging,
    int* __restrict__ off, int* __restrict__ adj)
{
    __shared__ int hist[BNODES];     // becomes exclusive offsets, then cursors
    __shared__ int psum[256];
    __shared__ int adj_st[CAP];
    int tid = threadIdx.x;
    int b = blockIdx.x;
    int e0 = g_boff[b], e1 = g_boff[b + 1];
    int cnt = e1 - e0;
    int node_base = b * BNODES;

    hist[tid] = 0; hist[tid + 256] = 0;
    __syncthreads();
    for (int i = tid; i < cnt; i += 256)
        atomicAdd(&hist[staging[e0 + i] >> 18], 1);
    __syncthreads();

    int h0 = hist[2 * tid], h1 = hist[2 * tid + 1];
    psum[tid] = h0 + h1;
    __syncthreads();
    for (int d = 1; d < 256; d <<= 1) {
        int t = (tid >= d) ? psum[tid - d] : 0;
        __syncthreads();
        psum[tid] += t;
        __syncthreads();
    }
    int ex0 = psum[tid] - (h0 + h1);
    int ex1 = ex0 + h0;
    int n0 = node_base + 2 * tid;
    if (n0 < NN)     off[n0]     = e0 + ex0;
    if (n0 + 1 < NN) off[n0 + 1] = e0 + ex1;
    if (b == NB - 1 && tid == 0) off[NN] = e1;
    __syncthreads();
    hist[2 * tid] = ex0; hist[2 * tid + 1] = ex1;   // reuse as cursors
    __syncthreads();

    if (cnt <= CAP) {
        for (int i = tid; i < cnt; i += 256) {
            int v = staging[e0 + i];
            int p = atomicAdd(&hist[v >> 18], 1);
            adj_st[p] = v & 0x3FFFF;
        }
        __syncthreads();
        for (int i = tid; i < cnt; i += 256) adj[e0 + i] = adj_st[i];
    } else {  // statistically unreachable fallback
        for (int i = tid; i < cnt; i += 256) {
            int v = staging[e0 + i];
            int p = atomicAdd(&hist[v >> 18], 1);
            adj[e0 + p] = v & 0x3FFFF;
        }
    }
}

// ================= f32 -> bf16 conversion (both tables, one dispatch) =========
__global__ __launch_bounds__(256) void cvt_kernel(
    const float4* __restrict__ inU, const float4* __restrict__ inI,
    ushort4* __restrict__ outU, ushort4* __restrict__ outI, int n4)
{
    int i = blockIdx.x * 256 + threadIdx.x;
    const float4* in;
    ushort4* out;
    if (i < n4) { in = inU; out = outU; }
    else        { in = inI; out = outI; i -= n4; if (i >= n4) return; }
    float4 v = in[i];
    ushort4 h;
    h.x = f2bf(v.x); h.y = f2bf(v.y); h.z = f2bf(v.z); h.w = f2bf(v.w);
    out[i] = h;
}

// ================= pull aggregation (one wave per node, bf16 in, bf16 mean out) ====
// Lanes 0-31 fetch neighbor A, lanes 32-63 fetch neighbor B (128 B rows);
// each lane holds feature pair (2*hl, 2*hl+1); xor-32 combine at the end.
__global__ __launch_bounds__(256) void pull_kernel(
    const int* __restrict__ off, const int* __restrict__ adj,
    const u16* __restrict__ xu16, const u16* __restrict__ xi16,
    u16* __restrict__ agg_u, u16* __restrict__ agg_i)
{
    int wid = (int)((blockIdx.x * 256 + threadIdx.x) >> 6);
    int lane = threadIdx.x & 63;
    if (wid >= NN) return;
    const u16* table;
    u16* out;
    int node;
    if (wid < NU) { node = wid;      table = xi16; out = agg_u; }
    else          { node = wid - NU; table = xu16; out = agg_i; }
    int beg = off[wid], end = off[wid + 1];
    int half = lane >> 5;
    int hl = lane & 31;
    float2 a0 = {0.f, 0.f}, a1 = {0.f, 0.f}, a2 = {0.f, 0.f}, a3 = {0.f, 0.f};
    for (int k = beg; k < end; k += 64) {
        int nk = min(64, end - k);
        int nb = (lane < nk) ? adj[k + lane] : 0;
        int t = 0;
        for (; t + 8 <= nk; t += 8) {
            int n0 = __shfl(nb, t + 0 + half);
            int n1 = __shfl(nb, t + 2 + half);
            int n2 = __shfl(nb, t + 4 + half);
            int n3 = __shfl(nb, t + 6 + half);
            unsigned int w0 = *(const unsigned int*)&table[(size_t)n0 * H + hl * 2];
            unsigned int w1 = *(const unsigned int*)&table[(size_t)n1 * H + hl * 2];
            unsigned int w2 = *(const unsigned int*)&table[(size_t)n2 * H + hl * 2];
            unsigned int w3 = *(const unsigned int*)&table[(size_t)n3 * H + hl * 2];
            a0.x += __uint_as_float(w0 << 16); a0.y += __uint_as_float(w0 & 0xFFFF0000u);
            a1.x += __uint_as_float(w1 << 16); a1.y += __uint_as_float(w1 & 0xFFFF0000u);
            a2.x += __uint_as_float(w2 << 16); a2.y += __uint_as_float(w2 & 0xFFFF0000u);
            a3.x += __uint_as_float(w3 << 16); a3.y += __uint_as_float(w3 & 0xFFFF0000u);
        }
        for (; t < nk; t += 2) {
            int idx = t + half;
            bool valid = idx < nk;
            int n = __shfl(nb, valid ? idx : t);
            unsigned int w = *(const unsigned int*)&table[(size_t)n * H + hl * 2];
            if (valid) {
                a0.x += __uint_as_float(w << 16);
                a0.y += __uint_as_float(w & 0xFFFF0000u);
            }
        }
    }
    float sx = (a0.x + a1.x) + (a2.x + a3.x);
    float sy = (a0.y + a1.y) + (a2.y + a3.y);
    sx += __shfl_xor(sx, 32);
    sy += __shfl_xor(sy, 32);
    if (half == 0) {
        int deg = end - beg;
        float inv = 1.0f / fmaxf((float)deg, 1.0f);
        unsigned int packed = ((unsigned int)f2bf(sy * inv) << 16) | f2bf(sx * inv);
        *(unsigned int*)&out[(size_t)node * H + hl * 2] = packed;
    }
}

// ================= register-tiled node update (users + items fused) ============
// relu(bn(agg_mean(bf16) @ Wll + bll + x_in @ Wlr)); 64 nodes x 64 feats per
// block, thread = 4 nodes x 4 feats. x_in is f32 (x32_*, layer 0) or bf16
// (x16_*, layer 1). Output bf16 only. Blocks [0,3125) users, [3125,6250) items.
__global__ __launch_bounds__(256) void update_kernel(
    const u16* __restrict__ agg_u, const u16* __restrict__ agg_i,
    const float* __restrict__ x32_u, const float* __restrict__ x32_i,
    const u16* __restrict__ x16_u, const u16* __restrict__ x16_i,
    u16* __restrict__ out_u, u16* __restrict__ out_i,
    const float* __restrict__ Wll_u, const float* __restrict__ bll_u,
    const float* __restrict__ Wlr_u,
    const float* __restrict__ g_u, const float* __restrict__ b_u,
    const float* __restrict__ m_u, const float* __restrict__ v_u,
    const float* __restrict__ Wll_i, const float* __restrict__ bll_i,
    const float* __restrict__ Wlr_i,
    const float* __restrict__ g_i, const float* __restrict__ b_i,
    const float* __restrict__ m_i, const float* __restrict__ v_i)
{
    __shared__ float sWll[32][68];
    __shared__ float sWlr[32][68];
    __shared__ float sA[64][36];
    __shared__ float sX[64][36];
    int tid = threadIdx.x;
    bool isU = blockIdx.x < (NU / 64);
    int node0 = (isU ? blockIdx.x : blockIdx.x - NU / 64) * 64;
    const u16*   agg16 = isU ? agg_u : agg_i;
    const float* x32   = isU ? x32_u : x32_i;
    const u16*   x16   = isU ? x16_u : x16_i;
    u16*         xout  = isU ? out_u : out_i;
    const float* Wll   = isU ? Wll_u : Wll_i;
    const float* bll   = isU ? bll_u : bll_i;
    const float* Wlr   = isU ? Wlr_u : Wlr_i;
    const float* bng   = isU ? g_u : g_i;
    const float* bnb   = isU ? b_u : b_i;
    const float* bnm   = isU ? m_u : m_i;
    const float* bnv   = isU ? v_u : v_i;

    int jt = (tid & 15) * 4;
    int nt = (tid >> 4) * 4;

    float4 b4 = *(const float4*)&bll[jt];
    float acc[4][4];
#pragma unroll
    for (int i = 0; i < 4; ++i) {
        acc[i][0] = b4.x; acc[i][1] = b4.y; acc[i][2] = b4.z; acc[i][3] = b4.w;
    }

    for (int kh = 0; kh < 2; ++kh) {
        int k0 = kh * 32;
        for (int idx = tid; idx < 32 * 64; idx += 256) {
            int kk = idx >> 6, j = idx & 63;
            sWll[kk][j] = Wll[(k0 + kk) * 64 + j];
            sWlr[kk][j] = Wlr[(k0 + kk) * 64 + j];
        }
        for (int idx = tid; idx < 64 * 16; idx += 256) {   // bf16 agg: uint pairs
            int r = idx >> 4, cp = idx & 15;
            unsigned int wv = *(const unsigned int*)&agg16[(size_t)(node0 + r) * H + k0 + cp * 2];
            sA[r][cp * 2]     = __uint_as_float(wv << 16);
            sA[r][cp * 2 + 1] = __uint_as_float(wv & 0xFFFF0000u);
        }
        if (x32) {
            for (int idx = tid; idx < 64 * 32; idx += 256) {
                int r = idx >> 5, c = idx & 31;
                sX[r][c] = x32[(size_t)(node0 + r) * H + k0 + c];
            }
        } else {
            for (int idx = tid; idx < 64 * 16; idx += 256) {
                int r = idx >> 4, cp = idx & 15;
                unsigned int wv = *(const unsigned int*)&x16[(size_t)(node0 + r) * H + k0 + cp * 2];
                sX[r][cp * 2]     = __uint_as_float(wv << 16);
                sX[r][cp * 2 + 1] = __uint_as_float(wv & 0xFFFF0000u);
            }
        }
        __syncthreads();
        for (int kk = 0; kk < 32; kk += 4) {
            float a[4][4], x[4][4];
#pragma unroll
            for (int i = 0; i < 4; ++i) {
                float4 t = *(const float4*)&sA[nt + i][kk];
                a[i][0] = t.x; a[i][1] = t.y; a[i][2] = t.z; a[i][3] = t.w;
                float4 u = *(const float4*)&sX[nt + i][kk];
                x[i][0] = u.x; x[i][1] = u.y; x[i][2] = u.z; x[i][3] = u.w;
            }
#pragma unroll
            for (int q = 0; q < 4; ++q) {
                float4 wl = *(const float4*)&sWll[kk + q][jt];
                float4 wr = *(const float4*)&sWlr[kk + q][jt];
                float wlv[4] = {wl.x, wl.y, wl.z, wl.w};
                float wrv[4] = {wr.x, wr.y, wr.z, wr.w};
#pragma unroll
                for (int i = 0; i < 4; ++i)
#pragma unroll
                    for (int j = 0; j < 4; ++j)
                        acc[i][j] += a[i][q] * wlv[j] + x[i][q] * wrv[j];
            }
        }
        __syncthreads();
    }

    float4 g4 = *(const float4*)&bng[jt];
    float4 bb4 = *(const float4*)&bnb[jt];
    float4 m4 = *(const float4*)&bnm[jt];
    float4 v4 = *(const float4*)&bnv[jt];
    float gv[4] = {g4.x, g4.y, g4.z, g4.w};
    float bv[4] = {bb4.x, bb4.y, bb4.z, bb4.w};
    float mv[4] = {m4.x, m4.y, m4.z, m4.w};
    float rv[4] = {rsqrtf(v4.x + EPSF), rsqrtf(v4.y + EPSF),
                   rsqrtf(v4.z + EPSF), rsqrtf(v4.w + EPSF)};
#pragma unroll
    for (int i = 0; i < 4; ++i) {
        int node = node0 + nt + i;
        ushort4 h;
        h.x = f2bf(fmaxf((acc[i][0] - mv[0]) * rv[0] * gv[0] + bv[0], 0.f));
        h.y = f2bf(fmaxf((acc[i][1] - mv[1]) * rv[1] * gv[1] + bv[1], 0.f));
        h.z = f2bf(fmaxf((acc[i][2] - mv[2]) * rv[2] * gv[2] + bv[2], 0.f));
        h.w = f2bf(fmaxf((acc[i][3] - mv[3]) * rv[3] * gv[3] + bv[3], 0.f));
        *(ushort4*)&xout[(size_t)node * H + jt] = h;
    }
}

// ================= MLP head (register-tiled fc1, LDS fc2, bf16 gathers) ========
__global__ __launch_bounds__(256) void mlp_kernel(
    const int* __restrict__ eli,
    const u16* __restrict__ xu16, const u16* __restrict__ xi16,
    const float* __restrict__ fc1w, const float* __restrict__ fc1b,
    const float* __restrict__ fc2w, const float* __restrict__ fc2b,
    float* __restrict__ out, int n)
{
    __shared__ float sW[32][68];
    __shared__ float sA[64][36];
    __shared__ float sH[64][68];
    __shared__ int   sid[128];
    __shared__ float sW2[256];
    int tid = threadIdx.x;
    int p0 = blockIdx.x * 64;
    if (tid < 128) {
        int p = p0 + (tid & 63);
        int side = tid >> 6;
        sid[tid] = (p < n) ? eli[side * NP + p] : -1;
    }
    sW2[tid] = fc2w[tid];
    __syncthreads();

    int jt = (tid & 15) * 4;
    int pt = (tid >> 4) * 4;
    float4 b4 = *(const float4*)&fc1b[jt];
    float acc[4][4];
#pragma unroll
    for (int i = 0; i < 4; ++i) {
        acc[i][0] = b4.x; acc[i][1] = b4.y; acc[i][2] = b4.z; acc[i][3] = b4.w;
    }

    for (int ch = 0; ch < 4; ++ch) {
        int k0 = ch * 32;
        const u16* tab = (ch < 2) ? xu16 : xi16;
        int idbase = (ch < 2) ? 0 : 64;
        int koff = (ch & 1) * 32;
        for (int idx = tid; idx < 64 * 16; idx += 256) {
            int r = idx >> 4, cp = idx & 15;
            int id = sid[idbase + r];
            unsigned int wv = (id >= 0)
                ? *(const unsigned int*)&tab[(size_t)id * H + koff + cp * 2] : 0u;
            sA[r][cp * 2]     = __uint_as_float(wv << 16);
            sA[r][cp * 2 + 1] = __uint_as_float(wv & 0xFFFF0000u);
        }
        for (int idx = tid; idx < 32 * 64; idx += 256) {
            int kk = idx >> 6, j = idx & 63;
            sW[kk][j] = fc1w[(k0 + kk) * 64 + j];
        }
        __syncthreads();
        for (int kk = 0; kk < 32; kk += 4) {
            float a[4][4];
#pragma unroll
            for (int i = 0; i < 4; ++i) {
                float4 t = *(const float4*)&sA[pt + i][kk];
                a[i][0] = t.x; a[i][1] = t.y; a[i][2] = t.z; a[i][3] = t.w;
            }
#pragma unroll
            for (int q = 0; q < 4; ++q) {
                float4 w = *(const float4*)&sW[kk + q][jt];
                float wv[4] = {w.x, w.y, w.z, w.w};
#pragma unroll
                for (int i = 0; i < 4; ++i)
#pragma unroll
                    for (int j = 0; j < 4; ++j)
                        acc[i][j] += a[i][q] * wv[j];
            }
        }
        __syncthreads();
    }

#pragma unroll
    for (int i = 0; i < 4; ++i)
#pragma unroll
        for (int j = 0; j < 4; ++j)
            sH[pt + i][jt + j] = fmaxf(acc[i][j], 0.f);
    __syncthreads();

    int pp = tid >> 2, c = tid & 3;
    float o = 0.f;
#pragma unroll
    for (int j = 0; j < 64; ++j) o += sH[pp][j] * sW2[j * 4 + c];
    int p = p0 + pp;
    if (p < n) out[(size_t)p * 4 + c] = o + fc2b[c];
}

extern "C" void kernel_launch(void* const* d_in, const int* in_sizes, int n_in,
                              void* d_out, int out_size, void* d_ws, size_t ws_size,
                              hipStream_t stream) {
    const int*   edge_index = (const int*)d_in[0];
    const int*   eli        = (const int*)d_in[1];
    const float* user_emb   = (const float*)d_in[2];
    const float* item_emb   = (const float*)d_in[3];
    const float* u_ll_w     = (const float*)d_in[4];
    const float* u_ll_b     = (const float*)d_in[5];
    const float* u_lr_w     = (const float*)d_in[6];
    const float* i_ll_w     = (const float*)d_in[7];
    const float* i_ll_b     = (const float*)d_in[8];
    const float* i_lr_w     = (const float*)d_in[9];
    const float* u_bn_g     = (const float*)d_in[10];
    const float* u_bn_b     = (const float*)d_in[11];
    const float* u_bn_m     = (const float*)d_in[12];
    const float* u_bn_v     = (const float*)d_in[13];
    const float* i_bn_g     = (const float*)d_in[14];
    const float* i_bn_b     = (const float*)d_in[15];
    const float* i_bn_m     = (const float*)d_in[16];
    const float* i_bn_v     = (const float*)d_in[17];
    const float* fc1_w      = (const float*)d_in[18];
    const float* fc1_b      = (const float*)d_in[19];
    const float* fc2_w      = (const float*)d_in[20];
    const float* fc2_b      = (const float*)d_in[21];
    float* out = (float*)d_out;

    const int* src = edge_index;
    const int* dst = edge_index + NE;

    // ---- workspace layout: 6 bf16 slots (153.6 MB) + adj (32) + small ≈ 187 MB
    //      (well under the ~238 MB proven-safe footprint) ----
    const size_t S = (size_t)NU * H;   // elems per slot
    char* w = (char*)d_ws;
    u16* f1 = (u16*)w;          w += 6 * S * 2;
    int* adj    = (int*)w;      w += (size_t)2 * NE * 4;
    int* off    = (int*)w;      w += (size_t)(NN + 1) * 4;
    int* g_bcnt = (int*)w;      w += (size_t)NB * 4;
    int* g_boff = (int*)w;      w += (size_t)(NB + 1) * 4;

    // Slot plan (25.6 MB each):
    //   s0/s1: emb16_u/i (cvt -> L0 pull)        -> fin16_u/i (L1 update -> mlp)
    //   s2/s3: staging (32 MB, CSR build)        -> agg16_u/i (both layers)
    //   s4/s5: blkhist (1.6 MB, head of s4)      -> xA16_u/i (L0 out, L1 gather+self)
    u16* emb16_u = f1 + 0 * S;
    u16* emb16_i = f1 + 1 * S;
    u16* fin16_u = f1 + 0 * S;
    u16* fin16_i = f1 + 1 * S;
    u16* agg16_u = f1 + 2 * S;
    u16* agg16_i = f1 + 3 * S;
    u16* xA16_u  = f1 + 4 * S;
    u16* xA16_i  = f1 + 5 * S;
    int* staging = (int*)(f1 + 2 * S);
    int* blkhist = (int*)(f1 + 4 * S);

    // ---- CSR build (no global atomics, no memsets) ----
    part1_kernel<<<PBLOCKS, 256, 0, stream>>>(src, dst, blkhist);
    colscan_kernel<<<NB, 256, 0, stream>>>(blkhist, g_bcnt);
    bucket_scan_kernel<<<1, 1024, 0, stream>>>(g_bcnt, g_boff);
    part2_kernel<<<PBLOCKS, 256, 0, stream>>>(src, dst, g_boff, blkhist, staging);
    bucket_fill_kernel<<<NB, 256, 0, stream>>>(g_boff, staging, off, adj);

    // ---- bf16 embeddings (both tables, one dispatch; staging dead now) ----
    const int n4 = NU * H / 4;
    cvt_kernel<<<(2 * n4 + 255) / 256, 256, 0, stream>>>(
        (const float4*)user_emb, (const float4*)item_emb,
        (ushort4*)emb16_u, (ushort4*)emb16_i, n4);

    const int pull_blocks = NN / 4;
    const int upd_blocks = (NU + NI) / 64;

    // ---- layer 0 (self path reads original f32 embeddings) ----
    pull_kernel<<<pull_blocks, 256, 0, stream>>>(
        off, adj, emb16_u, emb16_i, agg16_u, agg16_i);
    update_kernel<<<upd_blocks, 256, 0, stream>>>(
        agg16_u, agg16_i, user_emb, item_emb, (u16*)nullptr, (u16*)nullptr,
        xA16_u, xA16_i,
        u_ll_w, u_ll_b, u_lr_w, u_bn_g, u_bn_b, u_bn_m, u_bn_v,
        i_ll_w, i_ll_b, i_lr_w, i_bn_g, i_bn_b, i_bn_m, i_bn_v);

    // ---- layer 1 (gather + self path both bf16) ----
    pull_kernel<<<pull_blocks, 256, 0, stream>>>(
        off, adj, xA16_u, xA16_i, agg16_u, agg16_i);
    update_kernel<<<upd_blocks, 256, 0, stream>>>(
        agg16_u, agg16_i, (float*)nullptr, (float*)nullptr, xA16_u, xA16_i,
        fin16_u, fin16_i,
        u_ll_w + H * H, u_ll_b + H, u_lr_w + H * H,
        u_bn_g + H, u_bn_b + H, u_bn_m + H, u_bn_v + H,
        i_ll_w + H * H, i_ll_b + H, i_lr_w + H * H,
        i_bn_g + H, i_bn_b + H, i_bn_m + H, i_bn_v + H);

    // ---- MLP head ----
    mlp_kernel<<<(NP + 63) / 64, 256, 0, stream>>>(
        eli, fin16_u, fin16_i, fc1_w, fc1_b, fc2_w, fc2_b, out, NP);
}

// Round 9
// 704.916 us; speedup vs baseline: 3.7827x; 1.3263x over previous
//
#include <hip/hip_runtime.h>

#define NU 200000
#define NI 200000
#define NN 400000          // NU + NI (unified node space: users 0..NU-1, items NU..NN-1)
#define H 64
#define NE 4000000
#define NP 100000
#define EPSF 1e-5f

#define BSH 9              // nodes per bucket = 512
#define BNODES 512
#define NB ((NN + BNODES - 1) / BNODES)   // 782 buckets
#define CAP 15104          // LDS adj staging entries per bucket (mean 10240, sigma ~101)

#define PBLOCKS 512                          // partition blocks
#define EPB ((NE + PBLOCKS - 1) / PBLOCKS)   // 7813 edges per block slice

typedef unsigned short u16;
typedef __attribute__((ext_vector_type(8))) short bf16x8;
typedef __attribute__((ext_vector_type(4))) float f32x4;

__device__ __forceinline__ u16 f2bf(float f) {
    unsigned int b = __float_as_uint(f);
    b += 0x7FFFu + ((b >> 16) & 1u);     // round-to-nearest-even
    return (u16)(b >> 16);
}

// ================= CSR build (two-phase, LDS-atomic-only) =================

__global__ __launch_bounds__(256) void part1_kernel(
    const int* __restrict__ src, const int* __restrict__ dst,
    int* __restrict__ blkhist)
{
    __shared__ int hist[NB];
    int tid = threadIdx.x, blk = blockIdx.x;
    for (int i = tid; i < NB; i += 256) hist[i] = 0;
    __syncthreads();
    int e0 = blk * EPB, e1 = min(NE, e0 + EPB);
    for (int e = e0 + tid; e < e1; e += 256) {
        atomicAdd(&hist[src[e] >> BSH], 1);
        atomicAdd(&hist[(NU + dst[e]) >> BSH], 1);
    }
    __syncthreads();
    for (int i = tid; i < NB; i += 256)
        blkhist[(size_t)i * PBLOCKS + blk] = hist[i];
}

__global__ __launch_bounds__(256) void colscan_kernel(
    int* __restrict__ blkhist, int* __restrict__ g_bcnt)
{
    __shared__ int s[256];
    int b = blockIdx.x, tid = threadIdx.x;
    int* col = blkhist + (size_t)b * PBLOCKS;
    int v0 = col[2 * tid], v1 = col[2 * tid + 1];
    int ps = v0 + v1;
    s[tid] = ps;
    __syncthreads();
    for (int d = 1; d < 256; d <<= 1) {
        int t = (tid >= d) ? s[tid - d] : 0;
        __syncthreads();
        s[tid] += t;
        __syncthreads();
    }
    int ex = s[tid] - ps;   // exclusive over pairs
    col[2 * tid] = ex;
    col[2 * tid + 1] = ex + v0;
    if (tid == 255) g_bcnt[b] = s[255];
}

__global__ __launch_bounds__(1024) void bucket_scan_kernel(
    const int* __restrict__ g_bcnt, int* __restrict__ g_boff)
{
    __shared__ int s[1024];
    int tid = threadIdx.x;
    int v = (tid < NB) ? g_bcnt[tid] : 0;
    s[tid] = v;
    __syncthreads();
    for (int d = 1; d < 1024; d <<= 1) {
        int t = (tid >= d) ? s[tid - d] : 0;
        __syncthreads();
        s[tid] += t;
        __syncthreads();
    }
    if (tid < NB) g_boff[tid + 1] = s[tid];
    if (tid == 0) g_boff[0] = 0;
}

// entry = (local_node << 18) | neighbor   (local<512 -> 9 bits, nbr<200000 -> 18 bits)
__global__ __launch_bounds__(256) void part2_kernel(
    const int* __restrict__ src, const int* __restrict__ dst,
    const int* __restrict__ g_boff, const int* __restrict__ blkhist,
    int* __restrict__ staging)
{
    __shared__ int cur[NB];
    int tid = threadIdx.x, blk = blockIdx.x;
    for (int i = tid; i < NB; i += 256)
        cur[i] = g_boff[i] + blkhist[(size_t)i * PBLOCKS + blk];
    __syncthreads();
    int e0 = blk * EPB, e1 = min(NE, e0 + EPB);
    for (int e = e0 + tid; e < e1; e += 256) {
        int s = src[e], d = dst[e];
        int p1 = atomicAdd(&cur[s >> BSH], 1);
        staging[p1] = ((s & (BNODES - 1)) << 18) | d;
        int gn = NU + d;
        int p2 = atomicAdd(&cur[gn >> BSH], 1);
        staging[p2] = ((gn & (BNODES - 1)) << 18) | s;
    }
}

__global__ __launch_bounds__(256) void bucket_fill_kernel(
    const int* __restrict__ g_boff, const int* __restrict__ staging,
    int* __restrict__ off, int* __restrict__ adj)
{
    __shared__ int hist[BNODES];     // becomes exclusive offsets, then cursors
    __shared__ int psum[256];
    __shared__ int adj_st[CAP];
    int tid = threadIdx.x;
    int b = blockIdx.x;
    int e0 = g_boff[b], e1 = g_boff[b + 1];
    int cnt = e1 - e0;
    int node_base = b * BNODES;

    hist[tid] = 0; hist[tid + 256] = 0;
    __syncthreads();
    for (int i = tid; i < cnt; i += 256)
        atomicAdd(&hist[staging[e0 + i] >> 18], 1);
    __syncthreads();

    int h0 = hist[2 * tid], h1 = hist[2 * tid + 1];
    psum[tid] = h0 + h1;
    __syncthreads();
    for (int d = 1; d < 256; d <<= 1) {
        int t = (tid >= d) ? psum[tid - d] : 0;
        __syncthreads();
        psum[tid] += t;
        __syncthreads();
    }
    int ex0 = psum[tid] - (h0 + h1);
    int ex1 = ex0 + h0;
    int n0 = node_base + 2 * tid;
    if (n0 < NN)     off[n0]     = e0 + ex0;
    if (n0 + 1 < NN) off[n0 + 1] = e0 + ex1;
    if (b == NB - 1 && tid == 0) off[NN] = e1;
    __syncthreads();
    hist[2 * tid] = ex0; hist[2 * tid + 1] = ex1;   // reuse as cursors
    __syncthreads();

    if (cnt <= CAP) {
        for (int i = tid; i < cnt; i += 256) {
            int v = staging[e0 + i];
            int p = atomicAdd(&hist[v >> 18], 1);
            adj_st[p] = v & 0x3FFFF;
        }
        __syncthreads();
        for (int i = tid; i < cnt; i += 256) adj[e0 + i] = adj_st[i];
    } else {  // statistically unreachable fallback
        for (int i = tid; i < cnt; i += 256) {
            int v = staging[e0 + i];
            int p = atomicAdd(&hist[v >> 18], 1);
            adj[e0 + p] = v & 0x3FFFF;
        }
    }
}

// ================= f32 -> bf16 conversion (both tables, one dispatch) =========
__global__ __launch_bounds__(256) void cvt_kernel(
    const float4* __restrict__ inU, const float4* __restrict__ inI,
    ushort4* __restrict__ outU, ushort4* __restrict__ outI, int n4)
{
    int i = blockIdx.x * 256 + threadIdx.x;
    const float4* in;
    ushort4* out;
    if (i < n4) { in = inU; out = outU; }
    else        { in = inI; out = outI; i -= n4; if (i >= n4) return; }
    float4 v = in[i];
    ushort4 h;
    h.x = f2bf(v.x); h.y = f2bf(v.y); h.z = f2bf(v.z); h.w = f2bf(v.w);
    out[i] = h;
}

// ================= weight prep: stacked transposed bf16 weights + BN fold =====
// wcat[l][t][feat][k]: k<64 -> Wll[l,t][k][feat], k>=64 -> Wlr[l,t][k-64][feat]
// scsh[l][t][half][j]: half0 = g*rsqrt(v+eps), half1 = (bll-m)*sc + b
__global__ __launch_bounds__(256) void wcvt_kernel(
    const float* __restrict__ u_ll_w, const float* __restrict__ u_lr_w,
    const float* __restrict__ i_ll_w, const float* __restrict__ i_lr_w,
    const float* __restrict__ u_ll_b, const float* __restrict__ i_ll_b,
    const float* __restrict__ u_g, const float* __restrict__ u_b,
    const float* __restrict__ u_m, const float* __restrict__ u_v,
    const float* __restrict__ i_g, const float* __restrict__ i_b,
    const float* __restrict__ i_m, const float* __restrict__ i_v,
    u16* __restrict__ wcat, float* __restrict__ scsh)
{
    int idx = blockIdx.x * 256 + threadIdx.x;
    if (idx < 32768) {
        int k = idx & 127, f = (idx >> 7) & 63, t = (idx >> 13) & 1, l = idx >> 14;
        const float* W = t ? (k < 64 ? i_ll_w : i_lr_w)
                           : (k < 64 ? u_ll_w : u_lr_w);
        wcat[idx] = f2bf(W[l * 4096 + (k & 63) * 64 + f]);
    }
    if (idx < 512) {
        int j = idx & 63, half = (idx >> 6) & 1, t = (idx >> 7) & 1, l = idx >> 8;
        const float *g = t ? i_g : u_g, *b = t ? i_b : u_b;
        const float *m = t ? i_m : u_m, *v = t ? i_v : u_v;
        const float *bl = t ? i_ll_b : u_ll_b;
        float sc = g[l * 64 + j] * rsqrtf(v[l * 64 + j] + EPSF);
        scsh[idx] = half ? (bl[l * 64 + j] - m[l * 64 + j]) * sc + b[l * 64 + j]
                         : sc;
    }
}

// ================= pull aggregation (one wave per node, bf16 in, bf16 mean out) ====
__global__ __launch_bounds__(256) void pull_kernel(
    const int* __restrict__ off, const int* __restrict__ adj,
    const u16* __restrict__ xu16, const u16* __restrict__ xi16,
    u16* __restrict__ agg_u, u16* __restrict__ agg_i)
{
    int wid = (int)((blockIdx.x * 256 + threadIdx.x) >> 6);
    int lane = threadIdx.x & 63;
    if (wid >= NN) return;
    const u16* table;
    u16* out;
    int node;
    if (wid < NU) { node = wid;      table = xi16; out = agg_u; }
    else          { node = wid - NU; table = xu16; out = agg_i; }
    int beg = off[wid], end = off[wid + 1];
    int half = lane >> 5;
    int hl = lane & 31;
    float2 a0 = {0.f, 0.f}, a1 = {0.f, 0.f}, a2 = {0.f, 0.f}, a3 = {0.f, 0.f};
    for (int k = beg; k < end; k += 64) {
        int nk = min(64, end - k);
        int nb = (lane < nk) ? adj[k + lane] : 0;
        int t = 0;
        for (; t + 8 <= nk; t += 8) {
            int n0 = __shfl(nb, t + 0 + half);
            int n1 = __shfl(nb, t + 2 + half);
            int n2 = __shfl(nb, t + 4 + half);
            int n3 = __shfl(nb, t + 6 + half);
            unsigned int w0 = *(const unsigned int*)&table[(size_t)n0 * H + hl * 2];
            unsigned int w1 = *(const unsigned int*)&table[(size_t)n1 * H + hl * 2];
            unsigned int w2 = *(const unsigned int*)&table[(size_t)n2 * H + hl * 2];
            unsigned int w3 = *(const unsigned int*)&table[(size_t)n3 * H + hl * 2];
            a0.x += __uint_as_float(w0 << 16); a0.y += __uint_as_float(w0 & 0xFFFF0000u);
            a1.x += __uint_as_float(w1 << 16); a1.y += __uint_as_float(w1 & 0xFFFF0000u);
            a2.x += __uint_as_float(w2 << 16); a2.y += __uint_as_float(w2 & 0xFFFF0000u);
            a3.x += __uint_as_float(w3 << 16); a3.y += __uint_as_float(w3 & 0xFFFF0000u);
        }
        for (; t < nk; t += 2) {
            int idx = t + half;
            bool valid = idx < nk;
            int n = __shfl(nb, valid ? idx : t);
            unsigned int w = *(const unsigned int*)&table[(size_t)n * H + hl * 2];
            if (valid) {
                a0.x += __uint_as_float(w << 16);
                a0.y += __uint_as_float(w & 0xFFFF0000u);
            }
        }
    }
    float sx = (a0.x + a1.x) + (a2.x + a3.x);
    float sy = (a0.y + a1.y) + (a2.y + a3.y);
    sx += __shfl_xor(sx, 32);
    sy += __shfl_xor(sy, 32);
    if (half == 0) {
        int deg = end - beg;
        float inv = 1.0f / fmaxf((float)deg, 1.0f);
        unsigned int packed = ((unsigned int)f2bf(sy * inv) << 16) | f2bf(sx * inv);
        *(unsigned int*)&out[(size_t)node * H + hl * 2] = packed;
    }
}

// ================= MFMA node update (users + items fused) ======================
// out = relu( ([agg | x] @ [Wll;Wlr]) * sc + sh ), all operands bf16, acc f32.
// Block = 4 waves; wave computes a 16-node x 64-feat tile (16 MFMA 16x16x32).
// No LDS, no barriers. Blocks [0,3125) users, [3125,6250) items.
__global__ __launch_bounds__(256) void update_mfma_kernel(
    const u16* __restrict__ aggU, const u16* __restrict__ aggI,
    const u16* __restrict__ xU, const u16* __restrict__ xI,
    u16* __restrict__ outU, u16* __restrict__ outI,
    const u16* __restrict__ wcat,    // this layer: [2 types][64 feat][128 k]
    const float* __restrict__ scsh)  // this layer: [2 types][2][64]
{
    int tid = threadIdx.x;
    bool isU = blockIdx.x < (NU / 64);
    int nb = isU ? blockIdx.x : blockIdx.x - NU / 64;
    const u16* agg = isU ? aggU : aggI;
    const u16* x   = isU ? xU : xI;
    u16* out       = isU ? outU : outI;
    const u16* wt      = wcat + (isU ? 0 : 64 * 128);
    const float* sc_p  = scsh + (isU ? 0 : 128);
    const float* sh_p  = sc_p + 64;

    int wave = tid >> 6, lane = tid & 63;
    int row = lane & 15, g = lane >> 4;
    int node0 = nb * 64 + wave * 16;

    const u16* arow = agg + (size_t)(node0 + row) * H + g * 8;
    const u16* xrow = x   + (size_t)(node0 + row) * H + g * 8;
    bf16x8 a[4];
    a[0] = *(const bf16x8*)(arow);
    a[1] = *(const bf16x8*)(arow + 32);
    a[2] = *(const bf16x8*)(xrow);
    a[3] = *(const bf16x8*)(xrow + 32);

#pragma unroll
    for (int ct = 0; ct < 4; ++ct) {
        int feat = ct * 16 + row;
        const u16* wrow = wt + feat * 128 + g * 8;
        f32x4 acc = {0.f, 0.f, 0.f, 0.f};
#pragma unroll
        for (int kb = 0; kb < 4; ++kb) {
            bf16x8 b = *(const bf16x8*)(wrow + kb * 32);
            acc = __builtin_amdgcn_mfma_f32_16x16x32_bf16(a[kb], b, acc, 0, 0, 0);
        }
        float s = sc_p[feat], h = sh_p[feat];
#pragma unroll
        for (int r = 0; r < 4; ++r) {
            int node = node0 + g * 4 + r;   // D: col=lane&15, row=(lane>>4)*4+r
            float v = fmaxf(acc[r] * s + h, 0.f);
            out[(size_t)node * H + feat] = f2bf(v);
        }
    }
}

// ================= MLP head (register-tiled fc1, LDS fc2, bf16 gathers) ========
__global__ __launch_bounds__(256) void mlp_kernel(
    const int* __restrict__ eli,
    const u16* __restrict__ xu16, const u16* __restrict__ xi16,
    const float* __restrict__ fc1w, const float* __restrict__ fc1b,
    const float* __restrict__ fc2w, const float* __restrict__ fc2b,
    float* __restrict__ out, int n)
{
    __shared__ float sW[32][68];
    __shared__ float sA[64][36];
    __shared__ float sH[64][68];
    __shared__ int   sid[128];
    __shared__ float sW2[256];
    int tid = threadIdx.x;
    int p0 = blockIdx.x * 64;
    if (tid < 128) {
        int p = p0 + (tid & 63);
        int side = tid >> 6;
        sid[tid] = (p < n) ? eli[side * NP + p] : -1;
    }
    sW2[tid] = fc2w[tid];
    __syncthreads();

    int jt = (tid & 15) * 4;
    int pt = (tid >> 4) * 4;
    float4 b4 = *(const float4*)&fc1b[jt];
    float acc[4][4];
#pragma unroll
    for (int i = 0; i < 4; ++i) {
        acc[i][0] = b4.x; acc[i][1] = b4.y; acc[i][2] = b4.z; acc[i][3] = b4.w;
    }

    for (int ch = 0; ch < 4; ++ch) {
        int k0 = ch * 32;
        const u16* tab = (ch < 2) ? xu16 : xi16;
        int idbase = (ch < 2) ? 0 : 64;
        int koff = (ch & 1) * 32;
        for (int idx = tid; idx < 64 * 16; idx += 256) {
            int r = idx >> 4, cp = idx & 15;
            int id = sid[idbase + r];
            unsigned int wv = (id >= 0)
                ? *(const unsigned int*)&tab[(size_t)id * H + koff + cp * 2] : 0u;
            sA[r][cp * 2]     = __uint_as_float(wv << 16);
            sA[r][cp * 2 + 1] = __uint_as_float(wv & 0xFFFF0000u);
        }
        for (int idx = tid; idx < 32 * 64; idx += 256) {
            int kk = idx >> 6, j = idx & 63;
            sW[kk][j] = fc1w[(k0 + kk) * 64 + j];
        }
        __syncthreads();
        for (int kk = 0; kk < 32; kk += 4) {
            float a[4][4];
#pragma unroll
            for (int i = 0; i < 4; ++i) {
                float4 t = *(const float4*)&sA[pt + i][kk];
                a[i][0] = t.x; a[i][1] = t.y; a[i][2] = t.z; a[i][3] = t.w;
            }
#pragma unroll
            for (int q = 0; q < 4; ++q) {
                float4 w = *(const float4*)&sW[kk + q][jt];
                float wv[4] = {w.x, w.y, w.z, w.w};
#pragma unroll
                for (int i = 0; i < 4; ++i)
#pragma unroll
                    for (int j = 0; j < 4; ++j)
                        acc[i][j] += a[i][q] * wv[j];
            }
        }
        __syncthreads();
    }

#pragma unroll
    for (int i = 0; i < 4; ++i)
#pragma unroll
        for (int j = 0; j < 4; ++j)
            sH[pt + i][jt + j] = fmaxf(acc[i][j], 0.f);
    __syncthreads();

    int pp = tid >> 2, c = tid & 3;
    float o = 0.f;
#pragma unroll
    for (int j = 0; j < 64; ++j) o += sH[pp][j] * sW2[j * 4 + c];
    int p = p0 + pp;
    if (p < n) out[(size_t)p * 4 + c] = o + fc2b[c];
}

extern "C" void kernel_launch(void* const* d_in, const int* in_sizes, int n_in,
                              void* d_out, int out_size, void* d_ws, size_t ws_size,
                              hipStream_t stream) {
    const int*   edge_index = (const int*)d_in[0];
    const int*   eli        = (const int*)d_in[1];
    const float* user_emb   = (const float*)d_in[2];
    const float* item_emb   = (const float*)d_in[3];
    const float* u_ll_w     = (const float*)d_in[4];
    const float* u_ll_b     = (const float*)d_in[5];
    const float* u_lr_w     = (const float*)d_in[6];
    const float* i_ll_w     = (const float*)d_in[7];
    const float* i_ll_b     = (const float*)d_in[8];
    const float* i_lr_w     = (const float*)d_in[9];
    const float* u_bn_g     = (const float*)d_in[10];
    const float* u_bn_b     = (const float*)d_in[11];
    const float* u_bn_m     = (const float*)d_in[12];
    const float* u_bn_v     = (const float*)d_in[13];
    const float* i_bn_g     = (const float*)d_in[14];
    const float* i_bn_b     = (const float*)d_in[15];
    const float* i_bn_m     = (const float*)d_in[16];
    const float* i_bn_v     = (const float*)d_in[17];
    const float* fc1_w      = (const float*)d_in[18];
    const float* fc1_b      = (const float*)d_in[19];
    const float* fc2_w      = (const float*)d_in[20];
    const float* fc2_b      = (const float*)d_in[21];
    float* out = (float*)d_out;

    const int* src = edge_index;
    const int* dst = edge_index + NE;

    // ---- workspace: 6 bf16 slots (153.6 MB) + adj (32 MB) + small ≈ 187 MB ----
    const size_t S = (size_t)NU * H;   // elems per slot
    char* w = (char*)d_ws;
    u16* f1 = (u16*)w;          w += 6 * S * 2;
    int* adj    = (int*)w;      w += (size_t)2 * NE * 4;
    int* off    = (int*)w;      w += (size_t)(NN + 1) * 4;
    int* g_bcnt = (int*)w;      w += (size_t)NB * 4;
    int* g_boff = (int*)w;      w += (size_t)(NB + 1) * 4;
    u16* wcat   = (u16*)w;      w += (size_t)32768 * 2;   // [2][2][64][128] bf16
    float* scsh = (float*)w;    w += (size_t)512 * 4;     // [2][2][2][64] f32

    // Slot plan (25.6 MB each):
    //   s0/s1: emb16_u/i (cvt -> L0 pull + L0 self) -> fin16_u/i (L1 out -> mlp)
    //   s2/s3: staging (32 MB, CSR build)           -> agg16_u/i (both layers)
    //   s4/s5: blkhist (1.6 MB, head of s4)         -> xA16_u/i (L0 out)
    u16* emb16_u = f1 + 0 * S;
    u16* emb16_i = f1 + 1 * S;
    u16* fin16_u = f1 + 0 * S;
    u16* fin16_i = f1 + 1 * S;
    u16* agg16_u = f1 + 2 * S;
    u16* agg16_i = f1 + 3 * S;
    u16* xA16_u  = f1 + 4 * S;
    u16* xA16_i  = f1 + 5 * S;
    int* staging = (int*)(f1 + 2 * S);
    int* blkhist = (int*)(f1 + 4 * S);

    // ---- CSR build (no global atomics, no memsets) ----
    part1_kernel<<<PBLOCKS, 256, 0, stream>>>(src, dst, blkhist);
    colscan_kernel<<<NB, 256, 0, stream>>>(blkhist, g_bcnt);
    bucket_scan_kernel<<<1, 1024, 0, stream>>>(g_bcnt, g_boff);
    part2_kernel<<<PBLOCKS, 256, 0, stream>>>(src, dst, g_boff, blkhist, staging);
    bucket_fill_kernel<<<NB, 256, 0, stream>>>(g_boff, staging, off, adj);

    // ---- bf16 embeddings + prepped weights ----
    const int n4 = NU * H / 4;
    cvt_kernel<<<(2 * n4 + 255) / 256, 256, 0, stream>>>(
        (const float4*)user_emb, (const float4*)item_emb,
        (ushort4*)emb16_u, (ushort4*)emb16_i, n4);
    wcvt_kernel<<<128, 256, 0, stream>>>(
        u_ll_w, u_lr_w, i_ll_w, i_lr_w, u_ll_b, i_ll_b,
        u_bn_g, u_bn_b, u_bn_m, u_bn_v,
        i_bn_g, i_bn_b, i_bn_m, i_bn_v, wcat, scsh);

    const int pull_blocks = NN / 4;
    const int upd_blocks = (NU + NI) / 64;

    // ---- layer 0 ----
    pull_kernel<<<pull_blocks, 256, 0, stream>>>(
        off, adj, emb16_u, emb16_i, agg16_u, agg16_i);
    update_mfma_kernel<<<upd_blocks, 256, 0, stream>>>(
        agg16_u, agg16_i, emb16_u, emb16_i, xA16_u, xA16_i,
        wcat, scsh);

    // ---- layer 1 ----
    pull_kernel<<<pull_blocks, 256, 0, stream>>>(
        off, adj, xA16_u, xA16_i, agg16_u, agg16_i);
    update_mfma_kernel<<<upd_blocks, 256, 0, stream>>>(
        agg16_u, agg16_i, xA16_u, xA16_i, fin16_u, fin16_i,
        wcat + 16384, scsh + 256);

    // ---- MLP head ----
    mlp_kernel<<<(NP + 63) / 64, 256, 0, stream>>>(
        eli, fin16_u, fin16_i, fc1_w, fc1_b, fc2_w, fc2_b, out, NP);
}